// Round 5
// baseline (1734.043 us; speedup 1.0000x reference)
//
#include <hip/hip_runtime.h>
#include <hip/hip_bf16.h>
#include <math.h>

#define L      16384
#define CIN    200
#define CE     50
#define NS     4
#define KCL    256
#define WIN    64
#define NKEY   192

// ---------------------------------------------------------------------------
// conv3x3 reflect-pad -> x_embed (N, L, 50)
// grid (5 oc-groups of 10, 64 tiles, N), block 256 (16x16 pixel tile).
// Weights read via wave-uniform scalar loads (s_load) -> no LDS for weights.
// 4 input channels staged per iteration, register-prefetched (2 barriers/4ic).
// ---------------------------------------------------------------------------
__global__ __launch_bounds__(256) void k_conv3(const float* __restrict__ in,
                                               const float* __restrict__ Wx,
                                               float* __restrict__ xe) {
  const int ocg  = blockIdx.x;          // 0..4
  const int tile = blockIdx.y;          // 0..63
  const int n    = blockIdx.z;
  const int th = tile >> 3, tw = tile & 7;
  const int ty = threadIdx.x >> 4, tx = threadIdx.x & 15;
  const int oc0 = ocg * 10;
  const int tid = threadIdx.x;

  __shared__ __align__(16) float patch[4 * 18 * 20];   // 5.6 KB

  const float* inN = in + (size_t)n * CIN * L;
  const float* wB  = Wx + (size_t)oc0 * CIN * 9;

  // stage-invariant load pattern: 4*18*18 = 1296 halo elements
  int goff[6], loff[6];
#pragma unroll
  for (int j = 0; j < 6; ++j) {
    int idx = tid + j * 256;
    if (idx < 1296) {
      int ic = idx / 324, rem = idx % 324;
      int r = rem / 18, c = rem % 18;
      int gh = th * 16 + r - 1, gw = tw * 16 + c - 1;
      gh = gh < 0 ? -gh : (gh > 127 ? 254 - gh : gh);
      gw = gw < 0 ? -gw : (gw > 127 ? 254 - gw : gw);
      goff[j] = ic * L + gh * 128 + gw;
      loff[j] = ic * 360 + r * 20 + c;
    } else {
      goff[j] = -1;
      loff[j] = 0;
    }
  }

  float acc[10];
#pragma unroll
  for (int o = 0; o < 10; ++o) acc[o] = 0.f;

  float pf[6];
#pragma unroll
  for (int j = 0; j < 6; ++j) pf[j] = (goff[j] >= 0) ? inN[goff[j]] : 0.f;

  for (int s = 0; s < 50; ++s) {
    __syncthreads();                     // previous stage's LDS reads done
#pragma unroll
    for (int j = 0; j < 6; ++j)
      if (goff[j] >= 0) patch[loff[j]] = pf[j];
    __syncthreads();
    if (s < 49) {                        // prefetch next stage (overlaps compute)
      const float* src = inN + (size_t)(s + 1) * 4 * L;
#pragma unroll
      for (int j = 0; j < 6; ++j) pf[j] = (goff[j] >= 0) ? src[goff[j]] : 0.f;
    }

    float p[4][9];
#pragma unroll
    for (int icc = 0; icc < 4; ++icc) {
      const float* pb = &patch[icc * 360 + ty * 20 + tx];
#pragma unroll
      for (int dr = 0; dr < 3; ++dr)
#pragma unroll
        for (int dc = 0; dc < 3; ++dc)
          p[icc][dr * 3 + dc] = pb[dr * 20 + dc];
    }
    const float* wS = wB + (size_t)(4 * s) * 9;
#pragma unroll
    for (int o = 0; o < 10; ++o) {
      const float* wO = wS + (size_t)o * CIN * 9;   // uniform -> s_load
#pragma unroll
      for (int icc = 0; icc < 4; ++icc)
#pragma unroll
        for (int q = 0; q < 9; ++q)
          acc[o] = fmaf(p[icc][q], wO[icc * 9 + q], acc[o]);
    }
  }

  const int l = (th * 16 + ty) * 128 + (tw * 16 + tx);
  float* xrow = xe + ((size_t)n * L + l) * CE + oc0;
#pragma unroll
  for (int o = 0; o < 5; ++o)
    *(float2*)&xrow[o * 2] = make_float2(acc[o * 2], acc[o * 2 + 1]);
}

// ---------------------------------------------------------------------------
// 1x1 Wy -> y_embed (N, L, 200).  grid (256 l-tiles, N), block 256
// ---------------------------------------------------------------------------
__global__ __launch_bounds__(256) void k_wy(const float* __restrict__ in,
                                            const float* __restrict__ Wy,
                                            float* __restrict__ ye) {
  const int n  = blockIdx.y;
  const int l0 = blockIdx.x * 64;
  __shared__ __align__(16) float At[20][64];
  __shared__ __align__(16) float Wt[20][208];
  const int pg = threadIdx.x >> 4, og = threadIdx.x & 15;

  float acc[4][13];
#pragma unroll
  for (int p = 0; p < 4; ++p)
#pragma unroll
    for (int j = 0; j < 13; ++j) acc[p][j] = 0.f;

  // zero the oc padding columns once
  for (int idx = threadIdx.x; idx < 20 * 8; idx += 256)
    Wt[idx >> 3][200 + (idx & 7)] = 0.f;

  const float* inN = in + (size_t)n * CIN * L + l0;
  for (int c0 = 0; c0 < CIN; c0 += 20) {
    __syncthreads();
    for (int idx = threadIdx.x; idx < 20 * 64; idx += 256) {
      int k = idx >> 6, p = idx & 63;
      At[k][p] = inN[(size_t)(c0 + k) * L + p];
    }
    for (int idx = threadIdx.x; idx < 200 * 20; idx += 256) {
      int oc = idx / 20, k = idx % 20;
      Wt[k][oc] = Wy[(size_t)oc * CIN + c0 + k];
    }
    __syncthreads();
#pragma unroll
    for (int k = 0; k < 20; ++k) {
      float4 av = *(const float4*)&At[k][pg * 4];
      float a[4] = {av.x, av.y, av.z, av.w};
      float b[13];
#pragma unroll
      for (int j = 0; j < 13; ++j) b[j] = Wt[k][og * 13 + j];
#pragma unroll
      for (int p = 0; p < 4; ++p)
#pragma unroll
        for (int j = 0; j < 13; ++j) acc[p][j] = fmaf(a[p], b[j], acc[p][j]);
    }
  }
#pragma unroll
  for (int p = 0; p < 4; ++p) {
    int l = l0 + pg * 4 + p;
    float* yrow = ye + ((size_t)n * L + l) * CIN;
#pragma unroll
    for (int j = 0; j < 13; ++j) {
      int oc = og * 13 + j;
      if (oc < CIN) yrow[oc] = acc[p][j];
    }
  }
}

// ---------------------------------------------------------------------------
// Stable counting sort of keys (u*100+label) -> 128 buckets (b = u*32+label).
// ---------------------------------------------------------------------------
__global__ __launch_bounds__(256) void k_hist(const int* __restrict__ sl,
                                              int* __restrict__ hist) {
  const int blk = blockIdx.x;           // n*128 + chunk
  const int n = blk >> 7, ch = blk & 127;
  __shared__ int h[128];
  if (threadIdx.x < 128) h[threadIdx.x] = 0;
  __syncthreads();
#pragma unroll
  for (int it = 0; it < 2; ++it) {
    int pos = ch * 512 + it * 256 + threadIdx.x;      // [0, 65536)
    int u = pos >> 14, l = pos & (L - 1);
    int lab = sl[((size_t)n * NS + u) * L + l] & 31;
    atomicAdd(&h[u * 32 + lab], 1);
  }
  __syncthreads();
  if (threadIdx.x < 128) hist[(blk << 7) + threadIdx.x] = h[threadIdx.x];
}

__global__ __launch_bounds__(128) void k_scan(const int* __restrict__ hist,
                                              int* __restrict__ offs) {
  const int n = blockIdx.x, b = threadIdx.x;
  __shared__ int tot[128];
  __shared__ int basebuf[128];
  int t = 0;
  for (int c = 0; c < 128; ++c) t += hist[(((size_t)n * 128 + c) << 7) + b];
  tot[b] = t;
  __syncthreads();
  if (b == 0) {
    int run = 0;
    for (int i = 0; i < 128; ++i) { basebuf[i] = run; run += tot[i]; }
  }
  __syncthreads();
  int run = basebuf[b];
  for (int c = 0; c < 128; ++c) {
    offs[(((size_t)n * 128 + c) << 7) + b] = run;
    run += hist[(((size_t)n * 128 + c) << 7) + b];
  }
}

__global__ __launch_bounds__(512) void k_scatter(const int* __restrict__ sl,
                                                 const int* __restrict__ offs,
                                                 int* __restrict__ perm) {
  const int blk = blockIdx.x;
  const int n = blk >> 7, ch = blk & 127;
  const int tid = threadIdx.x, wv = tid >> 6, lane = tid & 63;
  __shared__ int wh[8][128];
  for (int idx = tid; idx < 1024; idx += 512) ((int*)wh)[idx] = 0;
  __syncthreads();
  const int pos = ch * 512 + tid;
  const int u = pos >> 14, l = pos & (L - 1);
  const int b = u * 32 + (sl[((size_t)n * NS + u) * L + l] & 31);
  atomicAdd(&wh[wv][b], 1);
  // stable within-wave rank among equal buckets
  int lr = 0;
  for (int s = 0; s < 64; ++s) {
    int ob = __shfl(b, s);
    lr += (s < lane && ob == b) ? 1 : 0;
  }
  __syncthreads();
  if (tid < 128) {                       // exclusive prefix across waves
    int run = 0;
#pragma unroll
    for (int w = 0; w < 8; ++w) { int v = wh[w][tid]; wh[w][tid] = run; run += v; }
  }
  __syncthreads();
  const int rank = offs[(blk << 7) + b] + wh[wv][b] + lr;
  perm[(size_t)n * (NS * L) + rank] = pos;
}

// ---------------------------------------------------------------------------
// Windowed attention, flash-style over three 64-key tiles.
// grid (256 k, 4 u, 2 n), block 512.  LDS ~45.6 KB -> 3 blocks/CU.
// PV reads ye directly from global (wave-uniform broadcast, L2/L3-resident).
// ---------------------------------------------------------------------------
#define PT_P  65
#define QS_P  68
#define KS_P  68

__global__ __launch_bounds__(512) void k_attn(const float* __restrict__ xe,
                                              const float* __restrict__ ye,
                                              const int* __restrict__ perm,
                                              float* __restrict__ attnO) {
  const int kcl = blockIdx.x;
  const int u   = blockIdx.y;
  const int n   = blockIdx.z;
  const int tid = threadIdx.x;

  __shared__ __align__(16) float Qst[CE * QS_P];     // 13600 B
  __shared__ __align__(16) float Kst[CE * KS_P];     // 13600 B
  __shared__ __align__(16) float Pt[WIN * PT_P];     // 16640 B
  __shared__ int   lidxS[NKEY];
  __shared__ float invn[WIN];
  __shared__ float rmaxS[WIN];
  __shared__ float rsumS[WIN];
  __shared__ float facS[WIN];

  if (tid < NKEY) {
    int kj = tid < 64 ? kcl
           : (tid < 128 ? ((kcl + KCL - 1) & (KCL - 1)) : ((kcl + 1) & (KCL - 1)));
    int p = (u << 14) + (kj << 6) + (tid & 63);
    lidxS[tid] = perm[(size_t)n * (NS * L) + p] & (L - 1);
  }
  if (tid < WIN) { rmaxS[tid] = -1e30f; rsumS[tid] = 0.f; }
  __syncthreads();

  // gather Q (rows 0..63, raw), stored transposed Qst[c][i]
  for (int idx = tid; idx < WIN * CE; idx += 512) {
    int j = idx / CE, c = idx % CE;
    Qst[c * QS_P + j] = xe[((size_t)n * L + lidxS[j]) * CE + c];
  }

  // thread mappings
  const int i_sm = tid >> 3, q_sm = tid & 7;     // softmax / norm: row, chunk
  const int ig = tid >> 5, jg = tid & 31;        // QK^T: i0=ig*4, j0=jg*2
  const int li = tid & 63, wq = tid >> 6;        // PV: row=li, e0=wq*28
  const int nf = (wq == 7) ? 1 : 7;              // valid float4s in e-slice

  float acc[28];
#pragma unroll
  for (int e = 0; e < 28; ++e) acc[e] = 0.f;

  for (int T = 0; T < 3; ++T) {
    const int jb = T * 64;
    __syncthreads();                    // Kst/Pt free for reuse
    // gather K tile (raw), transposed Kst[c][j]
    for (int idx = tid; idx < WIN * CE; idx += 512) {
      int j = idx / CE, c = idx % CE;
      Kst[c * KS_P + j] = xe[((size_t)n * L + lidxS[jb + j]) * CE + c];
    }
    __syncthreads();

    // row L2-norm factors (wave-parallel, 8 lanes per key row)
    {
      float s = 0.f;
      for (int c = q_sm; c < CE; c += 8) {
        float v = Kst[c * KS_P + i_sm];
        s = fmaf(v, v, s);
      }
      s += __shfl_xor(s, 1); s += __shfl_xor(s, 2); s += __shfl_xor(s, 4);
      if (q_sm == 0) invn[i_sm] = 1.f / fmaxf(sqrtf(s), 5e-5f);
    }
    __syncthreads();

    // S-tile = Q * K^T (64x64), fold invn, store transposed Pt[j][i]
    {
      float s00 = 0.f, s01 = 0.f, s10 = 0.f, s11 = 0.f, s20 = 0.f, s21 = 0.f,
            s30 = 0.f, s31 = 0.f;
      for (int c = 0; c < CE; ++c) {
        float4 qv = *(const float4*)&Qst[c * QS_P + ig * 4];
        float2 kv = *(const float2*)&Kst[c * KS_P + jg * 2];
        s00 = fmaf(qv.x, kv.x, s00); s01 = fmaf(qv.x, kv.y, s01);
        s10 = fmaf(qv.y, kv.x, s10); s11 = fmaf(qv.y, kv.y, s11);
        s20 = fmaf(qv.z, kv.x, s20); s21 = fmaf(qv.z, kv.y, s21);
        s30 = fmaf(qv.w, kv.x, s30); s31 = fmaf(qv.w, kv.y, s31);
      }
      float inv0 = invn[jg * 2], inv1 = invn[jg * 2 + 1];
      float* p0 = &Pt[(jg * 2 + 0) * PT_P + ig * 4];
      float* p1 = &Pt[(jg * 2 + 1) * PT_P + ig * 4];
      p0[0] = s00 * inv0; p0[1] = s10 * inv0; p0[2] = s20 * inv0; p0[3] = s30 * inv0;
      p1[0] = s01 * inv1; p1[1] = s11 * inv1; p1[2] = s21 * inv1; p1[3] = s31 * inv1;
    }
    __syncthreads();

    // online softmax update (row i_sm, j-chunk q_sm of 8)
    {
      float p[8];
      float tm = -1e30f;
#pragma unroll
      for (int k = 0; k < 8; ++k) {
        p[k] = Pt[(q_sm * 8 + k) * PT_P + i_sm];
        tm = fmaxf(tm, p[k]);
      }
      tm = fmaxf(tm, __shfl_xor(tm, 1));
      tm = fmaxf(tm, __shfl_xor(tm, 2));
      tm = fmaxf(tm, __shfl_xor(tm, 4));
      float mo = rmaxS[i_sm];
      float nm = fmaxf(mo, tm);
      float fc = __expf(mo - nm);
      float ts = 0.f;
#pragma unroll
      for (int k = 0; k < 8; ++k) {
        float v = __expf(p[k] - nm);
        Pt[(q_sm * 8 + k) * PT_P + i_sm] = v;
        ts += v;
      }
      ts += __shfl_xor(ts, 1); ts += __shfl_xor(ts, 2); ts += __shfl_xor(ts, 4);
      if (q_sm == 0) {
        rmaxS[i_sm] = nm;
        rsumS[i_sm] = rsumS[i_sm] * fc + ts;
        facS[i_sm]  = fc;
      }
    }
    __syncthreads();

    // PV accumulate: acc = acc*fac + P_tile @ Y_tile (Y from global, broadcast)
    {
      float fc = facS[li];
#pragma unroll
      for (int e = 0; e < 28; ++e) acc[e] *= fc;
      const float* yeN = ye + (size_t)n * L * CIN + wq * 28;
#pragma unroll 4
      for (int jj = 0; jj < WIN; ++jj) {
        float p = Pt[jj * PT_P + li];
        const float* yrow = yeN + (size_t)lidxS[jb + jj] * CIN;
#pragma unroll
        for (int f = 0; f < 7; ++f) {
          if (f < nf) {
            float4 yv = *(const float4*)&yrow[f * 4];
            acc[f * 4 + 0] = fmaf(p, yv.x, acc[f * 4 + 0]);
            acc[f * 4 + 1] = fmaf(p, yv.y, acc[f * 4 + 1]);
            acc[f * 4 + 2] = fmaf(p, yv.z, acc[f * 4 + 2]);
            acc[f * 4 + 3] = fmaf(p, yv.w, acc[f * 4 + 3]);
          }
        }
      }
    }
  }

  // normalize by final softmax sum, scatter to attnO[n][u][l][e] (the unsort)
  {
    float is = 1.f / rsumS[li];
    const int l = lidxS[li];
    float* orow = attnO + (((size_t)(n * NS + u) * L) + l) * CIN + wq * 28;
#pragma unroll
    for (int f = 0; f < 7; ++f)
      if (f < nf)
        *(float4*)&orow[f * 4] = make_float4(acc[f * 4] * is, acc[f * 4 + 1] * is,
                                             acc[f * 4 + 2] * is, acc[f * 4 + 3] * is);
  }
}

// ---------------------------------------------------------------------------
// 1x1 Wout (K=800) + bias + residual -> out (N, 200, L). grid (256, N), block 256
// ---------------------------------------------------------------------------
__global__ __launch_bounds__(256) void k_wout(const float* __restrict__ attnO,
                                              const float* __restrict__ Wo,
                                              const float* __restrict__ bo,
                                              const float* __restrict__ in,
                                              float* __restrict__ out) {
  const int n  = blockIdx.y;
  const int l0 = blockIdx.x * 64;
  __shared__ __align__(16) char sm[44160];
  float* At = (float*)sm;            // [40][68]  10880 B
  float* Wt = (float*)(sm + 10880);  // [40][208] 33280 B
  const int pg = threadIdx.x >> 4, og = threadIdx.x & 15;
  const int tid = threadIdx.x;

  float acc[4][13];
#pragma unroll
  for (int p = 0; p < 4; ++p)
#pragma unroll
    for (int j = 0; j < 13; ++j) acc[p][j] = 0.f;

  for (int idx = tid; idx < 40 * 8; idx += 256)
    Wt[(idx >> 3) * 208 + 200 + (idx & 7)] = 0.f;

  for (int c0 = 0; c0 < 800; c0 += 40) {
    const int u = c0 / 200, e0 = c0 % 200;
    __syncthreads();
    for (int idx = tid; idx < 64 * 40; idx += 256) {
      int p = idx / 40, kk = idx % 40;
      At[kk * 68 + p] = attnO[(((size_t)(n * NS + u) * L) + l0 + p) * CIN + e0 + kk];
    }
    for (int idx = tid; idx < 200 * 40; idx += 256) {
      int oc = idx / 40, kk = idx % 40;
      Wt[kk * 208 + oc] = Wo[(size_t)oc * 800 + c0 + kk];
    }
    __syncthreads();
#pragma unroll 8
    for (int kk = 0; kk < 40; ++kk) {
      float4 av = *(const float4*)&At[kk * 68 + pg * 4];
      float a[4] = {av.x, av.y, av.z, av.w};
      float b[13];
#pragma unroll
      for (int j = 0; j < 13; ++j) b[j] = Wt[kk * 208 + og * 13 + j];
#pragma unroll
      for (int p = 0; p < 4; ++p)
#pragma unroll
        for (int j = 0; j < 13; ++j) acc[p][j] = fmaf(a[p], b[j], acc[p][j]);
    }
  }
  __syncthreads();

  // staged epilogue for coalesced stores
  float* Ot = (float*)sm;            // [104][64]
  for (int r = 0; r < 2; ++r) {
    const int ocb = r * 104;
    const int width = (r == 0) ? 104 : 96;
#pragma unroll
    for (int p = 0; p < 4; ++p)
#pragma unroll
      for (int j = 0; j < 13; ++j) {
        int oc = og * 13 + j;
        if (oc >= ocb && oc < ocb + width)
          Ot[(oc - ocb) * 64 + pg * 4 + p] = acc[p][j];
      }
    __syncthreads();
    for (int idx = tid; idx < width * 64; idx += 256) {
      int oc2 = idx >> 6, p = idx & 63;
      size_t o = ((size_t)n * CIN + ocb + oc2) * L + l0 + p;
      out[o] = Ot[oc2 * 64 + p] + bo[ocb + oc2] + in[o];
    }
    __syncthreads();
  }
}

// ---------------------------------------------------------------------------
extern "C" void kernel_launch(void* const* d_in, const int* in_sizes, int n_in,
                              void* d_out, int out_size, void* d_ws, size_t ws_size,
                              hipStream_t stream) {
  const float* in = (const float*)d_in[0];
  const int*   sl = (const int*)d_in[1];
  const float* Wx = (const float*)d_in[2];
  const float* Wy = (const float*)d_in[3];
  const float* Wo = (const float*)d_in[4];
  const float* bo = (const float*)d_in[5];
  float* out = (float*)d_out;

  // workspace layout (needs ~138.3 MB)
  float* xe   = (float*)d_ws;                           // 2*16384*50
  float* ye   = xe + (size_t)2 * L * CE;                // 2*16384*200
  float* attn = ye + (size_t)2 * L * CIN;               // 2*4*16384*200
  int*   perm = (int*)(attn + (size_t)2 * NS * L * CIN);
  int*   hist = perm + (size_t)2 * NS * L;
  int*   offs = hist + (size_t)2 * 128 * 128;

  k_conv3  <<<dim3(5, 64, 2),  256, 0, stream>>>(in, Wx, xe);
  k_wy     <<<dim3(256, 2),    256, 0, stream>>>(in, Wy, ye);
  k_hist   <<<256,             256, 0, stream>>>(sl, hist);
  k_scan   <<<2,               128, 0, stream>>>(hist, offs);
  k_scatter<<<256,             512, 0, stream>>>(sl, offs, perm);
  k_attn   <<<dim3(256, 4, 2), 512, 0, stream>>>(xe, ye, perm, attn);
  k_wout   <<<dim3(256, 2),    256, 0, stream>>>(attn, Wo, bo, in, out);
}

// Round 6
// 1275.270 us; speedup vs baseline: 1.3597x; 1.3597x over previous
//
#include <hip/hip_runtime.h>
#include <hip/hip_bf16.h>
#include <math.h>

#define L      16384
#define CIN    200
#define CE     50
#define NS     4
#define KCL    256
#define WIN    64
#define NKEY   192

// ---------------------------------------------------------------------------
// conv3x3 reflect-pad -> x_embed (N, L, 50)
// ---------------------------------------------------------------------------
__global__ __launch_bounds__(256) void k_conv3(const float* __restrict__ in,
                                               const float* __restrict__ Wx,
                                               float* __restrict__ xe) {
  const int ocg  = blockIdx.x;          // 0..4
  const int tile = blockIdx.y;          // 0..63
  const int n    = blockIdx.z;
  const int th = tile >> 3, tw = tile & 7;
  const int ty = threadIdx.x >> 4, tx = threadIdx.x & 15;
  const int oc0 = ocg * 10;
  const int tid = threadIdx.x;

  __shared__ __align__(16) float patch[4 * 18 * 20];   // 5.6 KB

  const float* inN = in + (size_t)n * CIN * L;
  const float* wB  = Wx + (size_t)oc0 * CIN * 9;

  int goff[6], loff[6];
#pragma unroll
  for (int j = 0; j < 6; ++j) {
    int idx = tid + j * 256;
    if (idx < 1296) {
      int ic = idx / 324, rem = idx % 324;
      int r = rem / 18, c = rem % 18;
      int gh = th * 16 + r - 1, gw = tw * 16 + c - 1;
      gh = gh < 0 ? -gh : (gh > 127 ? 254 - gh : gh);
      gw = gw < 0 ? -gw : (gw > 127 ? 254 - gw : gw);
      goff[j] = ic * L + gh * 128 + gw;
      loff[j] = ic * 360 + r * 20 + c;
    } else {
      goff[j] = -1;
      loff[j] = 0;
    }
  }

  float acc[10];
#pragma unroll
  for (int o = 0; o < 10; ++o) acc[o] = 0.f;

  float pf[6];
#pragma unroll
  for (int j = 0; j < 6; ++j) pf[j] = (goff[j] >= 0) ? inN[goff[j]] : 0.f;

  for (int s = 0; s < 50; ++s) {
    __syncthreads();
#pragma unroll
    for (int j = 0; j < 6; ++j)
      if (goff[j] >= 0) patch[loff[j]] = pf[j];
    __syncthreads();
    if (s < 49) {
      const float* src = inN + (size_t)(s + 1) * 4 * L;
#pragma unroll
      for (int j = 0; j < 6; ++j) pf[j] = (goff[j] >= 0) ? src[goff[j]] : 0.f;
    }

    float p[4][9];
#pragma unroll
    for (int icc = 0; icc < 4; ++icc) {
      const float* pb = &patch[icc * 360 + ty * 20 + tx];
#pragma unroll
      for (int dr = 0; dr < 3; ++dr)
#pragma unroll
        for (int dc = 0; dc < 3; ++dc)
          p[icc][dr * 3 + dc] = pb[dr * 20 + dc];
    }
    const float* wS = wB + (size_t)(4 * s) * 9;
#pragma unroll
    for (int o = 0; o < 10; ++o) {
      const float* wO = wS + (size_t)o * CIN * 9;   // uniform -> s_load
#pragma unroll
      for (int icc = 0; icc < 4; ++icc)
#pragma unroll
        for (int q = 0; q < 9; ++q)
          acc[o] = fmaf(p[icc][q], wO[icc * 9 + q], acc[o]);
    }
  }

  const int l = (th * 16 + ty) * 128 + (tw * 16 + tx);
  float* xrow = xe + ((size_t)n * L + l) * CE + oc0;
#pragma unroll
  for (int o = 0; o < 5; ++o)
    *(float2*)&xrow[o * 2] = make_float2(acc[o * 2], acc[o * 2 + 1]);
}

// ---------------------------------------------------------------------------
// 1x1 Wy -> y_embed (N, L, 200).  grid (256 l-tiles, N), block 256
// ---------------------------------------------------------------------------
__global__ __launch_bounds__(256) void k_wy(const float* __restrict__ in,
                                            const float* __restrict__ Wy,
                                            float* __restrict__ ye) {
  const int n  = blockIdx.y;
  const int l0 = blockIdx.x * 64;
  __shared__ __align__(16) float At[20][64];
  __shared__ __align__(16) float Wt[20][208];
  const int pg = threadIdx.x >> 4, og = threadIdx.x & 15;

  float acc[4][13];
#pragma unroll
  for (int p = 0; p < 4; ++p)
#pragma unroll
    for (int j = 0; j < 13; ++j) acc[p][j] = 0.f;

  for (int idx = threadIdx.x; idx < 20 * 8; idx += 256)
    Wt[idx >> 3][200 + (idx & 7)] = 0.f;

  const float* inN = in + (size_t)n * CIN * L + l0;
  for (int c0 = 0; c0 < CIN; c0 += 20) {
    __syncthreads();
    for (int idx = threadIdx.x; idx < 20 * 64; idx += 256) {
      int k = idx >> 6, p = idx & 63;
      At[k][p] = inN[(size_t)(c0 + k) * L + p];
    }
    for (int idx = threadIdx.x; idx < 200 * 20; idx += 256) {
      int oc = idx / 20, k = idx % 20;
      Wt[k][oc] = Wy[(size_t)oc * CIN + c0 + k];
    }
    __syncthreads();
#pragma unroll
    for (int k = 0; k < 20; ++k) {
      float4 av = *(const float4*)&At[k][pg * 4];
      float a[4] = {av.x, av.y, av.z, av.w};
      float b[13];
#pragma unroll
      for (int j = 0; j < 13; ++j) b[j] = Wt[k][og * 13 + j];
#pragma unroll
      for (int p = 0; p < 4; ++p)
#pragma unroll
        for (int j = 0; j < 13; ++j) acc[p][j] = fmaf(a[p], b[j], acc[p][j]);
    }
  }
#pragma unroll
  for (int p = 0; p < 4; ++p) {
    int l = l0 + pg * 4 + p;
    float* yrow = ye + ((size_t)n * L + l) * CIN;
#pragma unroll
    for (int j = 0; j < 13; ++j) {
      int oc = og * 13 + j;
      if (oc < CIN) yrow[oc] = acc[p][j];
    }
  }
}

// ---------------------------------------------------------------------------
// Stable counting sort of keys (u*100+label) -> 128 buckets (b = u*32+label).
// ---------------------------------------------------------------------------
__global__ __launch_bounds__(256) void k_hist(const int* __restrict__ sl,
                                              int* __restrict__ hist) {
  const int blk = blockIdx.x;           // n*128 + chunk
  const int n = blk >> 7, ch = blk & 127;
  __shared__ int h[128];
  if (threadIdx.x < 128) h[threadIdx.x] = 0;
  __syncthreads();
#pragma unroll
  for (int it = 0; it < 2; ++it) {
    int pos = ch * 512 + it * 256 + threadIdx.x;      // [0, 65536)
    int u = pos >> 14, l = pos & (L - 1);
    int lab = sl[((size_t)n * NS + u) * L + l] & 31;
    atomicAdd(&h[u * 32 + lab], 1);
  }
  __syncthreads();
  if (threadIdx.x < 128) hist[(blk << 7) + threadIdx.x] = h[threadIdx.x];
}

__global__ __launch_bounds__(128) void k_scan(const int* __restrict__ hist,
                                              int* __restrict__ offs) {
  const int n = blockIdx.x, b = threadIdx.x;
  __shared__ int tot[128];
  __shared__ int basebuf[128];
  int t = 0;
  for (int c = 0; c < 128; ++c) t += hist[(((size_t)n * 128 + c) << 7) + b];
  tot[b] = t;
  __syncthreads();
  if (b == 0) {
    int run = 0;
    for (int i = 0; i < 128; ++i) { basebuf[i] = run; run += tot[i]; }
  }
  __syncthreads();
  int run = basebuf[b];
  for (int c = 0; c < 128; ++c) {
    offs[(((size_t)n * 128 + c) << 7) + b] = run;
    run += hist[(((size_t)n * 128 + c) << 7) + b];
  }
}

__global__ __launch_bounds__(512) void k_scatter(const int* __restrict__ sl,
                                                 const int* __restrict__ offs,
                                                 int* __restrict__ perm) {
  const int blk = blockIdx.x;
  const int n = blk >> 7, ch = blk & 127;
  const int tid = threadIdx.x, wv = tid >> 6, lane = tid & 63;
  __shared__ int wh[8][128];
  for (int idx = tid; idx < 1024; idx += 512) ((int*)wh)[idx] = 0;
  __syncthreads();
  const int pos = ch * 512 + tid;
  const int u = pos >> 14, l = pos & (L - 1);
  const int b = u * 32 + (sl[((size_t)n * NS + u) * L + l] & 31);
  atomicAdd(&wh[wv][b], 1);
  int lr = 0;
  for (int s = 0; s < 64; ++s) {
    int ob = __shfl(b, s);
    lr += (s < lane && ob == b) ? 1 : 0;
  }
  __syncthreads();
  if (tid < 128) {
    int run = 0;
#pragma unroll
    for (int w = 0; w < 8; ++w) { int v = wh[w][tid]; wh[w][tid] = run; run += v; }
  }
  __syncthreads();
  const int rank = offs[(blk << 7) + b] + wh[wv][b] + lr;
  perm[(size_t)n * (NS * L) + rank] = pos;
}

// ---------------------------------------------------------------------------
// Windowed attention, flash-style, e-split across 2 blocks per window.
// grid (256 k, 4 u, 4 (n*2+eh)), block 512.  LDS ~72.3 KB -> 2 blocks/CU.
// Block eh computes output cols [eh*100, eh*100+100); S/softmax duplicated.
// Y tile staged in LDS (uniform-broadcast reads in PV).
// ---------------------------------------------------------------------------
#define PT_P  65
#define QS_P  68
#define KS_P  68
#define YT_P  104
#define EHC   100

__global__ __launch_bounds__(512) void k_attn(const float* __restrict__ xe,
                                              const float* __restrict__ ye,
                                              const int* __restrict__ perm,
                                              float* __restrict__ attnO) {
  const int kcl = blockIdx.x;
  const int u   = blockIdx.y;
  const int n   = blockIdx.z >> 1;
  const int eh  = blockIdx.z & 1;
  const int tid = threadIdx.x;

  __shared__ __align__(16) float Qst[CE * QS_P];     // 13600 B
  __shared__ __align__(16) float Kst[CE * KS_P];     // 13600 B
  __shared__ __align__(16) float Pt[WIN * PT_P];     // 16640 B
  __shared__ __align__(16) float Yt[WIN * YT_P];     // 26624 B
  __shared__ int   lidxS[NKEY];
  __shared__ float invn[WIN];
  __shared__ float rmaxS[WIN];
  __shared__ float rsumS[WIN];
  __shared__ float facS[WIN];

  if (tid < NKEY) {
    int kj = tid < 64 ? kcl
           : (tid < 128 ? ((kcl + KCL - 1) & (KCL - 1)) : ((kcl + 1) & (KCL - 1)));
    int p = (u << 14) + (kj << 6) + (tid & 63);
    lidxS[tid] = perm[(size_t)n * (NS * L) + p] & (L - 1);
  }
  if (tid < WIN) { rmaxS[tid] = -1e30f; rsumS[tid] = 0.f; }
  __syncthreads();

  // gather Q (rows 0..63, raw), stored transposed Qst[c][i]
  for (int idx = tid; idx < WIN * CE; idx += 512) {
    int j = idx / CE, c = idx % CE;
    Qst[c * QS_P + j] = xe[((size_t)n * L + lidxS[j]) * CE + c];
  }

  // thread mappings
  const int i_sm = tid >> 3, q_sm = tid & 7;     // softmax / norm: row, chunk
  const int ig = tid >> 5, jg = tid & 31;        // QK^T: i0=ig*4, j0=jg*2
  const int li = tid & 63, wq = tid >> 6;        // PV: row=li, e0=wq*12
  const int e0 = wq * 12;
  const int nf4 = (wq == 7) ? 4 : 3;             // wave 7 covers cols 84..99

  float acc[16];
#pragma unroll
  for (int e = 0; e < 16; ++e) acc[e] = 0.f;

  const float* yeN = ye + (size_t)n * L * CIN + eh * EHC;

  for (int T = 0; T < 3; ++T) {
    const int jb = T * 64;
    __syncthreads();                    // Kst/Pt/Yt free for reuse
    // gather K tile (raw), transposed Kst[c][j]
    for (int idx = tid; idx < WIN * CE; idx += 512) {
      int j = idx / CE, c = idx % CE;
      Kst[c * KS_P + j] = xe[((size_t)n * L + lidxS[jb + j]) * CE + c];
    }
    // stage Y tile rows (this block's 100-col half), float4
    for (int idx = tid; idx < WIN * 25; idx += 512) {
      int j = idx / 25, c = idx % 25;
      *(float4*)&Yt[j * YT_P + c * 4] =
          *(const float4*)&yeN[(size_t)lidxS[jb + j] * CIN + c * 4];
    }
    __syncthreads();

    // row L2-norm factors (wave-parallel, 8 lanes per key row)
    {
      float s = 0.f;
      for (int c = q_sm; c < CE; c += 8) {
        float v = Kst[c * KS_P + i_sm];
        s = fmaf(v, v, s);
      }
      s += __shfl_xor(s, 1); s += __shfl_xor(s, 2); s += __shfl_xor(s, 4);
      if (q_sm == 0) invn[i_sm] = 1.f / fmaxf(sqrtf(s), 5e-5f);
    }
    __syncthreads();

    // S-tile = Q * K^T (64x64), fold invn, store transposed Pt[j][i]
    {
      float s00 = 0.f, s01 = 0.f, s10 = 0.f, s11 = 0.f, s20 = 0.f, s21 = 0.f,
            s30 = 0.f, s31 = 0.f;
      for (int c = 0; c < CE; ++c) {
        float4 qv = *(const float4*)&Qst[c * QS_P + ig * 4];
        float2 kv = *(const float2*)&Kst[c * KS_P + jg * 2];
        s00 = fmaf(qv.x, kv.x, s00); s01 = fmaf(qv.x, kv.y, s01);
        s10 = fmaf(qv.y, kv.x, s10); s11 = fmaf(qv.y, kv.y, s11);
        s20 = fmaf(qv.z, kv.x, s20); s21 = fmaf(qv.z, kv.y, s21);
        s30 = fmaf(qv.w, kv.x, s30); s31 = fmaf(qv.w, kv.y, s31);
      }
      float inv0 = invn[jg * 2], inv1 = invn[jg * 2 + 1];
      float* p0 = &Pt[(jg * 2 + 0) * PT_P + ig * 4];
      float* p1 = &Pt[(jg * 2 + 1) * PT_P + ig * 4];
      p0[0] = s00 * inv0; p0[1] = s10 * inv0; p0[2] = s20 * inv0; p0[3] = s30 * inv0;
      p1[0] = s01 * inv1; p1[1] = s11 * inv1; p1[2] = s21 * inv1; p1[3] = s31 * inv1;
    }
    __syncthreads();

    // online softmax update (row i_sm, j-chunk q_sm of 8)
    {
      float p[8];
      float tm = -1e30f;
#pragma unroll
      for (int k = 0; k < 8; ++k) {
        p[k] = Pt[(q_sm * 8 + k) * PT_P + i_sm];
        tm = fmaxf(tm, p[k]);
      }
      tm = fmaxf(tm, __shfl_xor(tm, 1));
      tm = fmaxf(tm, __shfl_xor(tm, 2));
      tm = fmaxf(tm, __shfl_xor(tm, 4));
      float mo = rmaxS[i_sm];
      float nm = fmaxf(mo, tm);
      float fc = __expf(mo - nm);
      float ts = 0.f;
#pragma unroll
      for (int k = 0; k < 8; ++k) {
        float v = __expf(p[k] - nm);
        Pt[(q_sm * 8 + k) * PT_P + i_sm] = v;
        ts += v;
      }
      ts += __shfl_xor(ts, 1); ts += __shfl_xor(ts, 2); ts += __shfl_xor(ts, 4);
      if (q_sm == 0) {
        rmaxS[i_sm] = nm;
        rsumS[i_sm] = rsumS[i_sm] * fc + ts;
        facS[i_sm]  = fc;
      }
    }
    __syncthreads();

    // PV accumulate from LDS: acc = acc*fac + P_tile @ Y_tile
    {
      float fc = facS[li];
#pragma unroll
      for (int e = 0; e < 16; ++e) acc[e] *= fc;
#pragma unroll 4
      for (int jj = 0; jj < WIN; ++jj) {
        float p = Pt[jj * PT_P + li];
        const float* yrow = &Yt[jj * YT_P + e0];
#pragma unroll
        for (int f = 0; f < 4; ++f) {
          if (f < nf4) {
            float4 yv = *(const float4*)&yrow[f * 4];
            acc[f * 4 + 0] = fmaf(p, yv.x, acc[f * 4 + 0]);
            acc[f * 4 + 1] = fmaf(p, yv.y, acc[f * 4 + 1]);
            acc[f * 4 + 2] = fmaf(p, yv.z, acc[f * 4 + 2]);
            acc[f * 4 + 3] = fmaf(p, yv.w, acc[f * 4 + 3]);
          }
        }
      }
    }
  }

  // normalize by final softmax sum, scatter to attnO[n][u][l][eh*100+e0..]
  {
    float is = 1.f / rsumS[li];
    const int l = lidxS[li];
    float* orow = attnO + (((size_t)(n * NS + u) * L) + l) * CIN + eh * EHC + e0;
#pragma unroll
    for (int f = 0; f < 4; ++f)
      if (f < nf4)
        *(float4*)&orow[f * 4] = make_float4(acc[f * 4] * is, acc[f * 4 + 1] * is,
                                             acc[f * 4 + 2] * is, acc[f * 4 + 3] * is);
  }
}

// ---------------------------------------------------------------------------
// 1x1 Wout (K=800) + bias + residual -> out (N, 200, L). grid (256, N), block 256
// ---------------------------------------------------------------------------
__global__ __launch_bounds__(256) void k_wout(const float* __restrict__ attnO,
                                              const float* __restrict__ Wo,
                                              const float* __restrict__ bo,
                                              const float* __restrict__ in,
                                              float* __restrict__ out) {
  const int n  = blockIdx.y;
  const int l0 = blockIdx.x * 64;
  __shared__ __align__(16) char sm[44160];
  float* At = (float*)sm;            // [40][68]  10880 B
  float* Wt = (float*)(sm + 10880);  // [40][208] 33280 B
  const int pg = threadIdx.x >> 4, og = threadIdx.x & 15;
  const int tid = threadIdx.x;

  float acc[4][13];
#pragma unroll
  for (int p = 0; p < 4; ++p)
#pragma unroll
    for (int j = 0; j < 13; ++j) acc[p][j] = 0.f;

  for (int idx = tid; idx < 40 * 8; idx += 256)
    Wt[(idx >> 3) * 208 + 200 + (idx & 7)] = 0.f;

  for (int c0 = 0; c0 < 800; c0 += 40) {
    const int u = c0 / 200, e0 = c0 % 200;
    __syncthreads();
    for (int idx = tid; idx < 64 * 40; idx += 256) {
      int p = idx / 40, kk = idx % 40;
      At[kk * 68 + p] = attnO[(((size_t)(n * NS + u) * L) + l0 + p) * CIN + e0 + kk];
    }
    for (int idx = tid; idx < 200 * 40; idx += 256) {
      int oc = idx / 40, kk = idx % 40;
      Wt[kk * 208 + oc] = Wo[(size_t)oc * 800 + c0 + kk];
    }
    __syncthreads();
#pragma unroll 8
    for (int kk = 0; kk < 40; ++kk) {
      float4 av = *(const float4*)&At[kk * 68 + pg * 4];
      float a[4] = {av.x, av.y, av.z, av.w};
      float b[13];
#pragma unroll
      for (int j = 0; j < 13; ++j) b[j] = Wt[kk * 208 + og * 13 + j];
#pragma unroll
      for (int p = 0; p < 4; ++p)
#pragma unroll
        for (int j = 0; j < 13; ++j) acc[p][j] = fmaf(a[p], b[j], acc[p][j]);
    }
  }
  __syncthreads();

  // staged epilogue for coalesced stores
  float* Ot = (float*)sm;            // [104][64]
  for (int r = 0; r < 2; ++r) {
    const int ocb = r * 104;
    const int width = (r == 0) ? 104 : 96;
#pragma unroll
    for (int p = 0; p < 4; ++p)
#pragma unroll
      for (int j = 0; j < 13; ++j) {
        int oc = og * 13 + j;
        if (oc >= ocb && oc < ocb + width)
          Ot[(oc - ocb) * 64 + pg * 4 + p] = acc[p][j];
      }
    __syncthreads();
    for (int idx = tid; idx < width * 64; idx += 256) {
      int oc2 = idx >> 6, p = idx & 63;
      size_t o = ((size_t)n * CIN + ocb + oc2) * L + l0 + p;
      out[o] = Ot[oc2 * 64 + p] + bo[ocb + oc2] + in[o];
    }
    __syncthreads();
  }
}

// ---------------------------------------------------------------------------
extern "C" void kernel_launch(void* const* d_in, const int* in_sizes, int n_in,
                              void* d_out, int out_size, void* d_ws, size_t ws_size,
                              hipStream_t stream) {
  const float* in = (const float*)d_in[0];
  const int*   sl = (const int*)d_in[1];
  const float* Wx = (const float*)d_in[2];
  const float* Wy = (const float*)d_in[3];
  const float* Wo = (const float*)d_in[4];
  const float* bo = (const float*)d_in[5];
  float* out = (float*)d_out;

  // workspace layout (needs ~138.3 MB)
  float* xe   = (float*)d_ws;                           // 2*16384*50
  float* ye   = xe + (size_t)2 * L * CE;                // 2*16384*200
  float* attn = ye + (size_t)2 * L * CIN;               // 2*4*16384*200
  int*   perm = (int*)(attn + (size_t)2 * NS * L * CIN);
  int*   hist = perm + (size_t)2 * NS * L;
  int*   offs = hist + (size_t)2 * 128 * 128;

  k_conv3  <<<dim3(5, 64, 2),  256, 0, stream>>>(in, Wx, xe);
  k_wy     <<<dim3(256, 2),    256, 0, stream>>>(in, Wy, ye);
  k_hist   <<<256,             256, 0, stream>>>(sl, hist);
  k_scan   <<<2,               128, 0, stream>>>(hist, offs);
  k_scatter<<<256,             512, 0, stream>>>(sl, offs, perm);
  k_attn   <<<dim3(256, 4, 4), 512, 0, stream>>>(xe, ye, perm, attn);
  k_wout   <<<dim3(256, 2),    256, 0, stream>>>(attn, Wo, bo, in, out);
}

// Round 7
// 1111.580 us; speedup vs baseline: 1.5600x; 1.1473x over previous
//
#include <hip/hip_runtime.h>
#include <hip/hip_bf16.h>
#include <math.h>

#define L      16384
#define CIN    200
#define CE     50
#define NS     4
#define KCL    256
#define WIN    64
#define NKEY   192

// ---------------------------------------------------------------------------
// conv3x3 reflect-pad -> x_embed (N, L, 50)
// ---------------------------------------------------------------------------
__global__ __launch_bounds__(256) void k_conv3(const float* __restrict__ in,
                                               const float* __restrict__ Wx,
                                               float* __restrict__ xe) {
  const int ocg  = blockIdx.x;          // 0..4
  const int tile = blockIdx.y;          // 0..63
  const int n    = blockIdx.z;
  const int th = tile >> 3, tw = tile & 7;
  const int ty = threadIdx.x >> 4, tx = threadIdx.x & 15;
  const int oc0 = ocg * 10;
  const int tid = threadIdx.x;

  __shared__ __align__(16) float patch[4 * 18 * 20];   // 5.6 KB

  const float* inN = in + (size_t)n * CIN * L;
  const float* wB  = Wx + (size_t)oc0 * CIN * 9;

  int goff[6], loff[6];
#pragma unroll
  for (int j = 0; j < 6; ++j) {
    int idx = tid + j * 256;
    if (idx < 1296) {
      int ic = idx / 324, rem = idx % 324;
      int r = rem / 18, c = rem % 18;
      int gh = th * 16 + r - 1, gw = tw * 16 + c - 1;
      gh = gh < 0 ? -gh : (gh > 127 ? 254 - gh : gh);
      gw = gw < 0 ? -gw : (gw > 127 ? 254 - gw : gw);
      goff[j] = ic * L + gh * 128 + gw;
      loff[j] = ic * 360 + r * 20 + c;
    } else {
      goff[j] = -1;
      loff[j] = 0;
    }
  }

  float acc[10];
#pragma unroll
  for (int o = 0; o < 10; ++o) acc[o] = 0.f;

  float pf[6];
#pragma unroll
  for (int j = 0; j < 6; ++j) pf[j] = (goff[j] >= 0) ? inN[goff[j]] : 0.f;

  for (int s = 0; s < 50; ++s) {
    __syncthreads();
#pragma unroll
    for (int j = 0; j < 6; ++j)
      if (goff[j] >= 0) patch[loff[j]] = pf[j];
    __syncthreads();
    if (s < 49) {
      const float* src = inN + (size_t)(s + 1) * 4 * L;
#pragma unroll
      for (int j = 0; j < 6; ++j) pf[j] = (goff[j] >= 0) ? src[goff[j]] : 0.f;
    }

    float p[4][9];
#pragma unroll
    for (int icc = 0; icc < 4; ++icc) {
      const float* pb = &patch[icc * 360 + ty * 20 + tx];
#pragma unroll
      for (int dr = 0; dr < 3; ++dr)
#pragma unroll
        for (int dc = 0; dc < 3; ++dc)
          p[icc][dr * 3 + dc] = pb[dr * 20 + dc];
    }
    const float* wS = wB + (size_t)(4 * s) * 9;
#pragma unroll
    for (int o = 0; o < 10; ++o) {
      const float* wO = wS + (size_t)o * CIN * 9;   // uniform -> s_load
#pragma unroll
      for (int icc = 0; icc < 4; ++icc)
#pragma unroll
        for (int q = 0; q < 9; ++q)
          acc[o] = fmaf(p[icc][q], wO[icc * 9 + q], acc[o]);
    }
  }

  const int l = (th * 16 + ty) * 128 + (tw * 16 + tx);
  float* xrow = xe + ((size_t)n * L + l) * CE + oc0;
#pragma unroll
  for (int o = 0; o < 5; ++o)
    *(float2*)&xrow[o * 2] = make_float2(acc[o * 2], acc[o * 2 + 1]);
}

// ---------------------------------------------------------------------------
// 1x1 Wy -> y_embed (N, L, 200).  grid (256 l-tiles, N), block 256
// ---------------------------------------------------------------------------
__global__ __launch_bounds__(256) void k_wy(const float* __restrict__ in,
                                            const float* __restrict__ Wy,
                                            float* __restrict__ ye) {
  const int n  = blockIdx.y;
  const int l0 = blockIdx.x * 64;
  __shared__ __align__(16) float At[20][64];
  __shared__ __align__(16) float Wt[20][208];
  const int pg = threadIdx.x >> 4, og = threadIdx.x & 15;

  float acc[4][13];
#pragma unroll
  for (int p = 0; p < 4; ++p)
#pragma unroll
    for (int j = 0; j < 13; ++j) acc[p][j] = 0.f;

  for (int idx = threadIdx.x; idx < 20 * 8; idx += 256)
    Wt[idx >> 3][200 + (idx & 7)] = 0.f;

  const float* inN = in + (size_t)n * CIN * L + l0;
  for (int c0 = 0; c0 < CIN; c0 += 20) {
    __syncthreads();
    for (int idx = threadIdx.x; idx < 20 * 64; idx += 256) {
      int k = idx >> 6, p = idx & 63;
      At[k][p] = inN[(size_t)(c0 + k) * L + p];
    }
    for (int idx = threadIdx.x; idx < 200 * 20; idx += 256) {
      int oc = idx / 20, k = idx % 20;
      Wt[k][oc] = Wy[(size_t)oc * CIN + c0 + k];
    }
    __syncthreads();
#pragma unroll
    for (int k = 0; k < 20; ++k) {
      float4 av = *(const float4*)&At[k][pg * 4];
      float a[4] = {av.x, av.y, av.z, av.w};
      float b[13];
#pragma unroll
      for (int j = 0; j < 13; ++j) b[j] = Wt[k][og * 13 + j];
#pragma unroll
      for (int p = 0; p < 4; ++p)
#pragma unroll
        for (int j = 0; j < 13; ++j) acc[p][j] = fmaf(a[p], b[j], acc[p][j]);
    }
  }
#pragma unroll
  for (int p = 0; p < 4; ++p) {
    int l = l0 + pg * 4 + p;
    float* yrow = ye + ((size_t)n * L + l) * CIN;
#pragma unroll
    for (int j = 0; j < 13; ++j) {
      int oc = og * 13 + j;
      if (oc < CIN) yrow[oc] = acc[p][j];
    }
  }
}

// ---------------------------------------------------------------------------
// Stable counting sort of keys (u*100+label) -> 128 buckets (b = u*32+label).
// ---------------------------------------------------------------------------
__global__ __launch_bounds__(256) void k_hist(const int* __restrict__ sl,
                                              int* __restrict__ hist) {
  const int blk = blockIdx.x;           // n*128 + chunk
  const int n = blk >> 7, ch = blk & 127;
  __shared__ int h[128];
  if (threadIdx.x < 128) h[threadIdx.x] = 0;
  __syncthreads();
#pragma unroll
  for (int it = 0; it < 2; ++it) {
    int pos = ch * 512 + it * 256 + threadIdx.x;      // [0, 65536)
    int u = pos >> 14, l = pos & (L - 1);
    int lab = sl[((size_t)n * NS + u) * L + l] & 31;
    atomicAdd(&h[u * 32 + lab], 1);
  }
  __syncthreads();
  if (threadIdx.x < 128) hist[(blk << 7) + threadIdx.x] = h[threadIdx.x];
}

__global__ __launch_bounds__(128) void k_scan(const int* __restrict__ hist,
                                              int* __restrict__ offs) {
  const int n = blockIdx.x, b = threadIdx.x;
  __shared__ int tot[128];
  __shared__ int basebuf[128];
  int t = 0;
  for (int c = 0; c < 128; ++c) t += hist[(((size_t)n * 128 + c) << 7) + b];
  tot[b] = t;
  __syncthreads();
  if (b == 0) {
    int run = 0;
    for (int i = 0; i < 128; ++i) { basebuf[i] = run; run += tot[i]; }
  }
  __syncthreads();
  int run = basebuf[b];
  for (int c = 0; c < 128; ++c) {
    offs[(((size_t)n * 128 + c) << 7) + b] = run;
    run += hist[(((size_t)n * 128 + c) << 7) + b];
  }
}

__global__ __launch_bounds__(512) void k_scatter(const int* __restrict__ sl,
                                                 const int* __restrict__ offs,
                                                 int* __restrict__ perm) {
  const int blk = blockIdx.x;
  const int n = blk >> 7, ch = blk & 127;
  const int tid = threadIdx.x, wv = tid >> 6, lane = tid & 63;
  __shared__ int wh[8][128];
  for (int idx = tid; idx < 1024; idx += 512) ((int*)wh)[idx] = 0;
  __syncthreads();
  const int pos = ch * 512 + tid;
  const int u = pos >> 14, l = pos & (L - 1);
  const int b = u * 32 + (sl[((size_t)n * NS + u) * L + l] & 31);
  atomicAdd(&wh[wv][b], 1);
  int lr = 0;
  for (int s = 0; s < 64; ++s) {
    int ob = __shfl(b, s);
    lr += (s < lane && ob == b) ? 1 : 0;
  }
  __syncthreads();
  if (tid < 128) {
    int run = 0;
#pragma unroll
    for (int w = 0; w < 8; ++w) { int v = wh[w][tid]; wh[w][tid] = run; run += v; }
  }
  __syncthreads();
  const int rank = offs[(blk << 7) + b] + wh[wv][b] + lr;
  perm[(size_t)n * (NS * L) + rank] = pos;
}

// ---------------------------------------------------------------------------
// Windowed attention, flash-style, e-split across 2 blocks per window.
// grid (256 k, 4 u, 4 (n*2+eh)), block 512.  LDS ~72.5 KB -> 2 blocks/CU.
// Round-6 restructure: fused gather+norm (shfl), softmax fused into S epilogue
// (3 barriers/tile), PV re-tiled 8 rows x 2 cols/thread (per-lane Y reads).
// ---------------------------------------------------------------------------
#define PT_P  68
#define QS_P  68
#define KS_P  68
#define YT_P  100
#define EHC   100

__global__ __launch_bounds__(512) void k_attn(const float* __restrict__ xe,
                                              const float* __restrict__ ye,
                                              const int* __restrict__ perm,
                                              float* __restrict__ attnO) {
  const int kcl = blockIdx.x;
  const int u   = blockIdx.y;
  const int n   = blockIdx.z >> 1;
  const int eh  = blockIdx.z & 1;
  const int tid = threadIdx.x;

  __shared__ __align__(16) float Qst[CE * QS_P];     // 13600 B
  __shared__ __align__(16) float Kst[CE * KS_P];     // 13600 B
  __shared__ __align__(16) float Pt[WIN * PT_P];     // 17408 B
  __shared__ __align__(16) float Yt[WIN * YT_P];     // 25600 B
  __shared__ int   lidxS[NKEY];
  __shared__ float rmaxS[WIN];
  __shared__ float rsumS[WIN];
  __shared__ float facS[WIN];

  if (tid < NKEY) {
    int kj = tid < 64 ? kcl
           : (tid < 128 ? ((kcl + KCL - 1) & (KCL - 1)) : ((kcl + 1) & (KCL - 1)));
    int p = (u << 14) + (kj << 6) + (tid & 63);
    lidxS[tid] = perm[(size_t)n * (NS * L) + p] & (L - 1);
  }
  if (tid < WIN) { rmaxS[tid] = -1e30f; rsumS[tid] = 0.f; }
  __syncthreads();

  // Q gather (raw): 8 lanes per row, transposed store Qst[c][j]
  {
    const int j = tid >> 3, c8 = tid & 7;
    const float* xrow = xe + ((size_t)n * L + lidxS[j]) * CE;
#pragma unroll
    for (int k = 0; k < 7; ++k) {
      int c = c8 + 8 * k;
      if (c < CE) Qst[c * QS_P + j] = xrow[c];
    }
  }

  // thread mappings
  const int ig = tid >> 5, jg = tid & 31;        // S: rows i0..i0+3, cols j0,j0+1
  const int i0 = ig * 4, j0 = jg * 2;
  const int rt = tid >> 6, lane = tid & 63;      // PV: rows r0..r0+7, cols e0,e0+1
  const int r0 = rt * 8, e0 = lane * 2;
  const bool pvact = lane < 50;

  float acc[8][2];
#pragma unroll
  for (int rr = 0; rr < 8; ++rr) { acc[rr][0] = 0.f; acc[rr][1] = 0.f; }

  const float* yeN = ye + (size_t)n * L * CIN + eh * EHC;

  for (int T = 0; T < 3; ++T) {
    const int jb = T * 64;
    if (T) __syncthreads();             // protect Kst/Yt/Pt from prev PV readers

    // K gather + fused L2-normalize (8 lanes per row, shfl_xor reduce)
    {
      const int j = tid >> 3, c8 = tid & 7;
      const float* xrow = xe + ((size_t)n * L + lidxS[jb + j]) * CE;
      float v[7];
      float ss = 0.f;
#pragma unroll
      for (int k = 0; k < 7; ++k) {
        int c = c8 + 8 * k;
        v[k] = (c < CE) ? xrow[c] : 0.f;
        ss = fmaf(v[k], v[k], ss);
      }
      ss += __shfl_xor(ss, 1); ss += __shfl_xor(ss, 2); ss += __shfl_xor(ss, 4);
      float inv = 1.f / fmaxf(sqrtf(ss), 5e-5f);
#pragma unroll
      for (int k = 0; k < 7; ++k) {
        int c = c8 + 8 * k;
        if (c < CE) Kst[c * KS_P + j] = v[k] * inv;
      }
    }
    // Y tile stage (this block's 100-col half), float4
    for (int idx = tid; idx < WIN * 25; idx += 512) {
      int j = idx / 25, c = idx % 25;
      *(float4*)&Yt[j * YT_P + c * 4] =
          *(const float4*)&yeN[(size_t)lidxS[jb + j] * CIN + c * 4];
    }
    __syncthreads();

    // S (64x64) + fused online softmax epilogue; Pt gets exp'd values
    {
      float s[4][2];
#pragma unroll
      for (int a = 0; a < 4; ++a) { s[a][0] = 0.f; s[a][1] = 0.f; }
      for (int c = 0; c < CE; ++c) {
        float4 qv = *(const float4*)&Qst[c * QS_P + i0];   // uniform broadcast
        float2 kv = *(const float2*)&Kst[c * KS_P + j0];   // per-lane
        s[0][0] = fmaf(qv.x, kv.x, s[0][0]); s[0][1] = fmaf(qv.x, kv.y, s[0][1]);
        s[1][0] = fmaf(qv.y, kv.x, s[1][0]); s[1][1] = fmaf(qv.y, kv.y, s[1][1]);
        s[2][0] = fmaf(qv.z, kv.x, s[2][0]); s[2][1] = fmaf(qv.z, kv.y, s[2][1]);
        s[3][0] = fmaf(qv.w, kv.x, s[3][0]); s[3][1] = fmaf(qv.w, kv.y, s[3][1]);
      }
      float nm[4], fc[4], ts[4];
#pragma unroll
      for (int a = 0; a < 4; ++a) {
        float tm = fmaxf(s[a][0], s[a][1]);
        tm = fmaxf(tm, __shfl_xor(tm, 1));
        tm = fmaxf(tm, __shfl_xor(tm, 2));
        tm = fmaxf(tm, __shfl_xor(tm, 4));
        tm = fmaxf(tm, __shfl_xor(tm, 8));
        tm = fmaxf(tm, __shfl_xor(tm, 16));
        float mo = rmaxS[i0 + a];
        nm[a] = fmaxf(mo, tm);
        fc[a] = __expf(mo - nm[a]);
        s[a][0] = __expf(s[a][0] - nm[a]);
        s[a][1] = __expf(s[a][1] - nm[a]);
        float t = s[a][0] + s[a][1];
        t += __shfl_xor(t, 1); t += __shfl_xor(t, 2); t += __shfl_xor(t, 4);
        t += __shfl_xor(t, 8); t += __shfl_xor(t, 16);
        ts[a] = t;
      }
      *(float4*)&Pt[(j0 + 0) * PT_P + i0] =
          make_float4(s[0][0], s[1][0], s[2][0], s[3][0]);
      *(float4*)&Pt[(j0 + 1) * PT_P + i0] =
          make_float4(s[0][1], s[1][1], s[2][1], s[3][1]);
      if (jg == 0) {
#pragma unroll
        for (int a = 0; a < 4; ++a) {
          rmaxS[i0 + a] = nm[a];
          rsumS[i0 + a] = rsumS[i0 + a] * fc[a] + ts[a];
          facS[i0 + a]  = fc[a];
        }
      }
    }
    __syncthreads();

    // PV: 8 rows x 2 cols per thread; P uniform b128, Y per-lane b64
    if (pvact) {
      float f8[8];
#pragma unroll
      for (int rr = 0; rr < 8; ++rr) f8[rr] = facS[r0 + rr];
#pragma unroll
      for (int rr = 0; rr < 8; ++rr) { acc[rr][0] *= f8[rr]; acc[rr][1] *= f8[rr]; }
#pragma unroll 4
      for (int k = 0; k < WIN; ++k) {
        float4 pA = *(const float4*)&Pt[k * PT_P + r0];
        float4 pB = *(const float4*)&Pt[k * PT_P + r0 + 4];
        float2 yv = *(const float2*)&Yt[k * YT_P + e0];
        acc[0][0] = fmaf(pA.x, yv.x, acc[0][0]); acc[0][1] = fmaf(pA.x, yv.y, acc[0][1]);
        acc[1][0] = fmaf(pA.y, yv.x, acc[1][0]); acc[1][1] = fmaf(pA.y, yv.y, acc[1][1]);
        acc[2][0] = fmaf(pA.z, yv.x, acc[2][0]); acc[2][1] = fmaf(pA.z, yv.y, acc[2][1]);
        acc[3][0] = fmaf(pA.w, yv.x, acc[3][0]); acc[3][1] = fmaf(pA.w, yv.y, acc[3][1]);
        acc[4][0] = fmaf(pB.x, yv.x, acc[4][0]); acc[4][1] = fmaf(pB.x, yv.y, acc[4][1]);
        acc[5][0] = fmaf(pB.y, yv.x, acc[5][0]); acc[5][1] = fmaf(pB.y, yv.y, acc[5][1]);
        acc[6][0] = fmaf(pB.z, yv.x, acc[6][0]); acc[6][1] = fmaf(pB.z, yv.y, acc[6][1]);
        acc[7][0] = fmaf(pB.w, yv.x, acc[7][0]); acc[7][1] = fmaf(pB.w, yv.y, acc[7][1]);
      }
    }
  }

  // normalize + scatter (the unsort); per-row wave-contiguous 400B stores
  if (pvact) {
#pragma unroll
    for (int rr = 0; rr < 8; ++rr) {
      float is = 1.f / rsumS[r0 + rr];
      float* orow = attnO + (((size_t)(n * NS + u) * L) + lidxS[r0 + rr]) * CIN
                  + eh * EHC + e0;
      *(float2*)orow = make_float2(acc[rr][0] * is, acc[rr][1] * is);
    }
  }
}

// ---------------------------------------------------------------------------
// 1x1 Wout (K=800) + bias + residual -> out (N, 200, L). grid (256, N), block 256
// ---------------------------------------------------------------------------
__global__ __launch_bounds__(256) void k_wout(const float* __restrict__ attnO,
                                              const float* __restrict__ Wo,
                                              const float* __restrict__ bo,
                                              const float* __restrict__ in,
                                              float* __restrict__ out) {
  const int n  = blockIdx.y;
  const int l0 = blockIdx.x * 64;
  __shared__ __align__(16) char sm[44160];
  float* At = (float*)sm;            // [40][68]  10880 B
  float* Wt = (float*)(sm + 10880);  // [40][208] 33280 B
  const int pg = threadIdx.x >> 4, og = threadIdx.x & 15;
  const int tid = threadIdx.x;

  float acc[4][13];
#pragma unroll
  for (int p = 0; p < 4; ++p)
#pragma unroll
    for (int j = 0; j < 13; ++j) acc[p][j] = 0.f;

  for (int idx = tid; idx < 40 * 8; idx += 256)
    Wt[(idx >> 3) * 208 + 200 + (idx & 7)] = 0.f;

  for (int c0 = 0; c0 < 800; c0 += 40) {
    const int u = c0 / 200, e0 = c0 % 200;
    __syncthreads();
    for (int idx = tid; idx < 64 * 40; idx += 256) {
      int p = idx / 40, kk = idx % 40;
      At[kk * 68 + p] = attnO[(((size_t)(n * NS + u) * L) + l0 + p) * CIN + e0 + kk];
    }
    for (int idx = tid; idx < 200 * 40; idx += 256) {
      int oc = idx / 40, kk = idx % 40;
      Wt[kk * 208 + oc] = Wo[(size_t)oc * 800 + c0 + kk];
    }
    __syncthreads();
#pragma unroll 8
    for (int kk = 0; kk < 40; ++kk) {
      float4 av = *(const float4*)&At[kk * 68 + pg * 4];
      float a[4] = {av.x, av.y, av.z, av.w};
      float b[13];
#pragma unroll
      for (int j = 0; j < 13; ++j) b[j] = Wt[kk * 208 + og * 13 + j];
#pragma unroll
      for (int p = 0; p < 4; ++p)
#pragma unroll
        for (int j = 0; j < 13; ++j) acc[p][j] = fmaf(a[p], b[j], acc[p][j]);
    }
  }
  __syncthreads();

  // staged epilogue for coalesced stores
  float* Ot = (float*)sm;            // [104][64]
  for (int r = 0; r < 2; ++r) {
    const int ocb = r * 104;
    const int width = (r == 0) ? 104 : 96;
#pragma unroll
    for (int p = 0; p < 4; ++p)
#pragma unroll
      for (int j = 0; j < 13; ++j) {
        int oc = og * 13 + j;
        if (oc >= ocb && oc < ocb + width)
          Ot[(oc - ocb) * 64 + pg * 4 + p] = acc[p][j];
      }
    __syncthreads();
    for (int idx = tid; idx < width * 64; idx += 256) {
      int oc2 = idx >> 6, p = idx & 63;
      size_t o = ((size_t)n * CIN + ocb + oc2) * L + l0 + p;
      out[o] = Ot[oc2 * 64 + p] + bo[ocb + oc2] + in[o];
    }
    __syncthreads();
  }
}

// ---------------------------------------------------------------------------
extern "C" void kernel_launch(void* const* d_in, const int* in_sizes, int n_in,
                              void* d_out, int out_size, void* d_ws, size_t ws_size,
                              hipStream_t stream) {
  const float* in = (const float*)d_in[0];
  const int*   sl = (const int*)d_in[1];
  const float* Wx = (const float*)d_in[2];
  const float* Wy = (const float*)d_in[3];
  const float* Wo = (const float*)d_in[4];
  const float* bo = (const float*)d_in[5];
  float* out = (float*)d_out;

  // workspace layout (needs ~138.3 MB)
  float* xe   = (float*)d_ws;                           // 2*16384*50
  float* ye   = xe + (size_t)2 * L * CE;                // 2*16384*200
  float* attn = ye + (size_t)2 * L * CIN;               // 2*4*16384*200
  int*   perm = (int*)(attn + (size_t)2 * NS * L * CIN);
  int*   hist = perm + (size_t)2 * NS * L;
  int*   offs = hist + (size_t)2 * 128 * 128;

  k_conv3  <<<dim3(5, 64, 2),  256, 0, stream>>>(in, Wx, xe);
  k_wy     <<<dim3(256, 2),    256, 0, stream>>>(in, Wy, ye);
  k_hist   <<<256,             256, 0, stream>>>(sl, hist);
  k_scan   <<<2,               128, 0, stream>>>(hist, offs);
  k_scatter<<<256,             512, 0, stream>>>(sl, offs, perm);
  k_attn   <<<dim3(256, 4, 4), 512, 0, stream>>>(xe, ye, perm, attn);
  k_wout   <<<dim3(256, 2),    256, 0, stream>>>(attn, Wo, bo, in, out);
}

// Round 8
// 1101.153 us; speedup vs baseline: 1.5748x; 1.0095x over previous
//
#include <hip/hip_runtime.h>
#include <hip/hip_bf16.h>
#include <math.h>

#define L      16384
#define CIN    200
#define CE     50
#define NS     4
#define KCL    256
#define WIN    64
#define NKEY   192

// ---------------------------------------------------------------------------
// conv3x3 reflect-pad -> x_embed (N, L, 50)
// grid (5 oc-groups of 10, 64 tiles, N), block 256 (16x16 pixel tile).
// Round-7: 8-ic stages (25), double-buffered patch (1 barrier/stage),
// row stride 24 (uniform 2-way bank access = free), weights via s_load.
// ---------------------------------------------------------------------------
#define ICS   8
#define RS    24          // row stride (floats)
#define ICSZ  (18 * RS)   // 432 floats per ic slice
#define BUFSZ (ICS * ICSZ)

__global__ __launch_bounds__(256) void k_conv3(const float* __restrict__ in,
                                               const float* __restrict__ Wx,
                                               float* __restrict__ xe) {
  const int ocg  = blockIdx.x;          // 0..4
  const int tile = blockIdx.y;          // 0..63
  const int n    = blockIdx.z;
  const int th = tile >> 3, tw = tile & 7;
  const int ty = threadIdx.x >> 4, tx = threadIdx.x & 15;
  const int oc0 = ocg * 10;
  const int tid = threadIdx.x;

  __shared__ __align__(16) float patch[2 * BUFSZ];   // 27.6 KB

  const float* inN = in + (size_t)n * CIN * L;
  const float* wB  = Wx + (size_t)oc0 * CIN * 9;

  // stage-invariant load pattern: 8*18*18 = 2592 halo elements, 11 slots/thread
  int goff[11], loff[11];
#pragma unroll
  for (int j = 0; j < 11; ++j) {
    int idx = tid + j * 256;
    if (idx < ICS * 324) {
      int ic = idx / 324, rem = idx % 324;
      int r = rem / 18, c = rem % 18;
      int gh = th * 16 + r - 1, gw = tw * 16 + c - 1;
      gh = gh < 0 ? -gh : (gh > 127 ? 254 - gh : gh);
      gw = gw < 0 ? -gw : (gw > 127 ? 254 - gw : gw);
      goff[j] = ic * L + gh * 128 + gw;
      loff[j] = ic * ICSZ + r * RS + c;
    } else {
      goff[j] = -1;
      loff[j] = 0;
    }
  }

  float acc[10];
#pragma unroll
  for (int o = 0; o < 10; ++o) acc[o] = 0.f;

  float pf[11];
#pragma unroll
  for (int j = 0; j < 11; ++j) pf[j] = (goff[j] >= 0) ? inN[goff[j]] : 0.f;

  for (int s = 0; s < CIN / ICS; ++s) {
    float* buf = &patch[(s & 1) * BUFSZ];
    // write staged channels (other buffer than stage s-1's readers)
#pragma unroll
    for (int j = 0; j < 11; ++j)
      if (goff[j] >= 0) buf[loff[j]] = pf[j];
    __syncthreads();                    // buf ready; prev compute long done
    if (s < CIN / ICS - 1) {            // prefetch next stage under compute
      const float* src = inN + (size_t)(s + 1) * ICS * L;
#pragma unroll
      for (int j = 0; j < 11; ++j) pf[j] = (goff[j] >= 0) ? src[goff[j]] : 0.f;
    }

#pragma unroll
    for (int icc = 0; icc < ICS; ++icc) {
      const float* pb = &buf[icc * ICSZ + ty * RS + tx];
      float p[9];
#pragma unroll
      for (int dr = 0; dr < 3; ++dr)
#pragma unroll
        for (int dc = 0; dc < 3; ++dc)
          p[dr * 3 + dc] = pb[dr * RS + dc];
      const float* wS = wB + (size_t)(ICS * s + icc) * 9;
#pragma unroll
      for (int o = 0; o < 10; ++o) {
        const float* wO = wS + (size_t)o * CIN * 9;   // uniform -> s_load
#pragma unroll
        for (int q = 0; q < 9; ++q)
          acc[o] = fmaf(p[q], wO[q], acc[o]);
      }
    }
    __syncthreads();                    // all reads of buf done before rewrite
  }

  const int l = (th * 16 + ty) * 128 + (tw * 16 + tx);
  float* xrow = xe + ((size_t)n * L + l) * CE + oc0;
#pragma unroll
  for (int o = 0; o < 5; ++o)
    *(float2*)&xrow[o * 2] = make_float2(acc[o * 2], acc[o * 2 + 1]);
}

// ---------------------------------------------------------------------------
// 1x1 Wy -> y_embed (N, L, 200).  grid (256 l-tiles, N), block 256
// ---------------------------------------------------------------------------
__global__ __launch_bounds__(256) void k_wy(const float* __restrict__ in,
                                            const float* __restrict__ Wy,
                                            float* __restrict__ ye) {
  const int n  = blockIdx.y;
  const int l0 = blockIdx.x * 64;
  __shared__ __align__(16) float At[20][64];
  __shared__ __align__(16) float Wt[20][208];
  const int pg = threadIdx.x >> 4, og = threadIdx.x & 15;

  float acc[4][13];
#pragma unroll
  for (int p = 0; p < 4; ++p)
#pragma unroll
    for (int j = 0; j < 13; ++j) acc[p][j] = 0.f;

  for (int idx = threadIdx.x; idx < 20 * 8; idx += 256)
    Wt[idx >> 3][200 + (idx & 7)] = 0.f;

  const float* inN = in + (size_t)n * CIN * L + l0;
  for (int c0 = 0; c0 < CIN; c0 += 20) {
    __syncthreads();
    for (int idx = threadIdx.x; idx < 20 * 64; idx += 256) {
      int k = idx >> 6, p = idx & 63;
      At[k][p] = inN[(size_t)(c0 + k) * L + p];
    }
    for (int idx = threadIdx.x; idx < 200 * 20; idx += 256) {
      int oc = idx / 20, k = idx % 20;
      Wt[k][oc] = Wy[(size_t)oc * CIN + c0 + k];
    }
    __syncthreads();
#pragma unroll
    for (int k = 0; k < 20; ++k) {
      float4 av = *(const float4*)&At[k][pg * 4];
      float a[4] = {av.x, av.y, av.z, av.w};
      float b[13];
#pragma unroll
      for (int j = 0; j < 13; ++j) b[j] = Wt[k][og * 13 + j];
#pragma unroll
      for (int p = 0; p < 4; ++p)
#pragma unroll
        for (int j = 0; j < 13; ++j) acc[p][j] = fmaf(a[p], b[j], acc[p][j]);
    }
  }
#pragma unroll
  for (int p = 0; p < 4; ++p) {
    int l = l0 + pg * 4 + p;
    float* yrow = ye + ((size_t)n * L + l) * CIN;
#pragma unroll
    for (int j = 0; j < 13; ++j) {
      int oc = og * 13 + j;
      if (oc < CIN) yrow[oc] = acc[p][j];
    }
  }
}

// ---------------------------------------------------------------------------
// Stable counting sort of keys (u*100+label) -> 128 buckets (b = u*32+label).
// ---------------------------------------------------------------------------
__global__ __launch_bounds__(256) void k_hist(const int* __restrict__ sl,
                                              int* __restrict__ hist) {
  const int blk = blockIdx.x;           // n*128 + chunk
  const int n = blk >> 7, ch = blk & 127;
  __shared__ int h[128];
  if (threadIdx.x < 128) h[threadIdx.x] = 0;
  __syncthreads();
#pragma unroll
  for (int it = 0; it < 2; ++it) {
    int pos = ch * 512 + it * 256 + threadIdx.x;      // [0, 65536)
    int u = pos >> 14, l = pos & (L - 1);
    int lab = sl[((size_t)n * NS + u) * L + l] & 31;
    atomicAdd(&h[u * 32 + lab], 1);
  }
  __syncthreads();
  if (threadIdx.x < 128) hist[(blk << 7) + threadIdx.x] = h[threadIdx.x];
}

__global__ __launch_bounds__(128) void k_scan(const int* __restrict__ hist,
                                              int* __restrict__ offs) {
  const int n = blockIdx.x, b = threadIdx.x;
  __shared__ int tot[128];
  __shared__ int basebuf[128];
  int t = 0;
  for (int c = 0; c < 128; ++c) t += hist[(((size_t)n * 128 + c) << 7) + b];
  tot[b] = t;
  __syncthreads();
  if (b == 0) {
    int run = 0;
    for (int i = 0; i < 128; ++i) { basebuf[i] = run; run += tot[i]; }
  }
  __syncthreads();
  int run = basebuf[b];
  for (int c = 0; c < 128; ++c) {
    offs[(((size_t)n * 128 + c) << 7) + b] = run;
    run += hist[(((size_t)n * 128 + c) << 7) + b];
  }
}

__global__ __launch_bounds__(512) void k_scatter(const int* __restrict__ sl,
                                                 const int* __restrict__ offs,
                                                 int* __restrict__ perm) {
  const int blk = blockIdx.x;
  const int n = blk >> 7, ch = blk & 127;
  const int tid = threadIdx.x, wv = tid >> 6, lane = tid & 63;
  __shared__ int wh[8][128];
  for (int idx = tid; idx < 1024; idx += 512) ((int*)wh)[idx] = 0;
  __syncthreads();
  const int pos = ch * 512 + tid;
  const int u = pos >> 14, l = pos & (L - 1);
  const int b = u * 32 + (sl[((size_t)n * NS + u) * L + l] & 31);
  atomicAdd(&wh[wv][b], 1);
  int lr = 0;
  for (int s = 0; s < 64; ++s) {
    int ob = __shfl(b, s);
    lr += (s < lane && ob == b) ? 1 : 0;
  }
  __syncthreads();
  if (tid < 128) {
    int run = 0;
#pragma unroll
    for (int w = 0; w < 8; ++w) { int v = wh[w][tid]; wh[w][tid] = run; run += v; }
  }
  __syncthreads();
  const int rank = offs[(blk << 7) + b] + wh[wv][b] + lr;
  perm[(size_t)n * (NS * L) + rank] = pos;
}

// ---------------------------------------------------------------------------
// Windowed attention, flash-style, e-split across 2 blocks per window.
// grid (256 k, 4 u, 4 (n*2+eh)), block 512.  LDS ~72.5 KB -> 2 blocks/CU.
// ---------------------------------------------------------------------------
#define PT_P  68
#define QS_P  68
#define KS_P  68
#define YT_P  100
#define EHC   100

__global__ __launch_bounds__(512) void k_attn(const float* __restrict__ xe,
                                              const float* __restrict__ ye,
                                              const int* __restrict__ perm,
                                              float* __restrict__ attnO) {
  const int kcl = blockIdx.x;
  const int u   = blockIdx.y;
  const int n   = blockIdx.z >> 1;
  const int eh  = blockIdx.z & 1;
  const int tid = threadIdx.x;

  __shared__ __align__(16) float Qst[CE * QS_P];     // 13600 B
  __shared__ __align__(16) float Kst[CE * KS_P];     // 13600 B
  __shared__ __align__(16) float Pt[WIN * PT_P];     // 17408 B
  __shared__ __align__(16) float Yt[WIN * YT_P];     // 25600 B
  __shared__ int   lidxS[NKEY];
  __shared__ float rmaxS[WIN];
  __shared__ float rsumS[WIN];
  __shared__ float facS[WIN];

  if (tid < NKEY) {
    int kj = tid < 64 ? kcl
           : (tid < 128 ? ((kcl + KCL - 1) & (KCL - 1)) : ((kcl + 1) & (KCL - 1)));
    int p = (u << 14) + (kj << 6) + (tid & 63);
    lidxS[tid] = perm[(size_t)n * (NS * L) + p] & (L - 1);
  }
  if (tid < WIN) { rmaxS[tid] = -1e30f; rsumS[tid] = 0.f; }
  __syncthreads();

  // Q gather (raw): 8 lanes per row, transposed store Qst[c][j]
  {
    const int j = tid >> 3, c8 = tid & 7;
    const float* xrow = xe + ((size_t)n * L + lidxS[j]) * CE;
#pragma unroll
    for (int k = 0; k < 7; ++k) {
      int c = c8 + 8 * k;
      if (c < CE) Qst[c * QS_P + j] = xrow[c];
    }
  }

  // thread mappings
  const int ig = tid >> 5, jg = tid & 31;        // S: rows i0..i0+3, cols j0,j0+1
  const int i0 = ig * 4, j0 = jg * 2;
  const int rt = tid >> 6, lane = tid & 63;      // PV: rows r0..r0+7, cols e0,e0+1
  const int r0 = rt * 8, e0 = lane * 2;
  const bool pvact = lane < 50;

  float acc[8][2];
#pragma unroll
  for (int rr = 0; rr < 8; ++rr) { acc[rr][0] = 0.f; acc[rr][1] = 0.f; }

  const float* yeN = ye + (size_t)n * L * CIN + eh * EHC;

  for (int T = 0; T < 3; ++T) {
    const int jb = T * 64;
    if (T) __syncthreads();             // protect Kst/Yt/Pt from prev PV readers

    // K gather + fused L2-normalize (8 lanes per row, shfl_xor reduce)
    {
      const int j = tid >> 3, c8 = tid & 7;
      const float* xrow = xe + ((size_t)n * L + lidxS[jb + j]) * CE;
      float v[7];
      float ss = 0.f;
#pragma unroll
      for (int k = 0; k < 7; ++k) {
        int c = c8 + 8 * k;
        v[k] = (c < CE) ? xrow[c] : 0.f;
        ss = fmaf(v[k], v[k], ss);
      }
      ss += __shfl_xor(ss, 1); ss += __shfl_xor(ss, 2); ss += __shfl_xor(ss, 4);
      float inv = 1.f / fmaxf(sqrtf(ss), 5e-5f);
#pragma unroll
      for (int k = 0; k < 7; ++k) {
        int c = c8 + 8 * k;
        if (c < CE) Kst[c * KS_P + j] = v[k] * inv;
      }
    }
    // Y tile stage (this block's 100-col half), float4
    for (int idx = tid; idx < WIN * 25; idx += 512) {
      int j = idx / 25, c = idx % 25;
      *(float4*)&Yt[j * YT_P + c * 4] =
          *(const float4*)&yeN[(size_t)lidxS[jb + j] * CIN + c * 4];
    }
    __syncthreads();

    // S (64x64) + fused online softmax epilogue; Pt gets exp'd values
    {
      float s[4][2];
#pragma unroll
      for (int a = 0; a < 4; ++a) { s[a][0] = 0.f; s[a][1] = 0.f; }
      for (int c = 0; c < CE; ++c) {
        float4 qv = *(const float4*)&Qst[c * QS_P + i0];   // uniform broadcast
        float2 kv = *(const float2*)&Kst[c * KS_P + j0];   // per-lane
        s[0][0] = fmaf(qv.x, kv.x, s[0][0]); s[0][1] = fmaf(qv.x, kv.y, s[0][1]);
        s[1][0] = fmaf(qv.y, kv.x, s[1][0]); s[1][1] = fmaf(qv.y, kv.y, s[1][1]);
        s[2][0] = fmaf(qv.z, kv.x, s[2][0]); s[2][1] = fmaf(qv.z, kv.y, s[2][1]);
        s[3][0] = fmaf(qv.w, kv.x, s[3][0]); s[3][1] = fmaf(qv.w, kv.y, s[3][1]);
      }
      float nm[4], fc[4], ts[4];
#pragma unroll
      for (int a = 0; a < 4; ++a) {
        float tm = fmaxf(s[a][0], s[a][1]);
        tm = fmaxf(tm, __shfl_xor(tm, 1));
        tm = fmaxf(tm, __shfl_xor(tm, 2));
        tm = fmaxf(tm, __shfl_xor(tm, 4));
        tm = fmaxf(tm, __shfl_xor(tm, 8));
        tm = fmaxf(tm, __shfl_xor(tm, 16));
        float mo = rmaxS[i0 + a];
        nm[a] = fmaxf(mo, tm);
        fc[a] = __expf(mo - nm[a]);
        s[a][0] = __expf(s[a][0] - nm[a]);
        s[a][1] = __expf(s[a][1] - nm[a]);
        float t = s[a][0] + s[a][1];
        t += __shfl_xor(t, 1); t += __shfl_xor(t, 2); t += __shfl_xor(t, 4);
        t += __shfl_xor(t, 8); t += __shfl_xor(t, 16);
        ts[a] = t;
      }
      *(float4*)&Pt[(j0 + 0) * PT_P + i0] =
          make_float4(s[0][0], s[1][0], s[2][0], s[3][0]);
      *(float4*)&Pt[(j0 + 1) * PT_P + i0] =
          make_float4(s[0][1], s[1][1], s[2][1], s[3][1]);
      if (jg == 0) {
#pragma unroll
        for (int a = 0; a < 4; ++a) {
          rmaxS[i0 + a] = nm[a];
          rsumS[i0 + a] = rsumS[i0 + a] * fc[a] + ts[a];
          facS[i0 + a]  = fc[a];
        }
      }
    }
    __syncthreads();

    // PV: 8 rows x 2 cols per thread; P uniform b128, Y per-lane b64
    if (pvact) {
      float f8[8];
#pragma unroll
      for (int rr = 0; rr < 8; ++rr) f8[rr] = facS[r0 + rr];
#pragma unroll
      for (int rr = 0; rr < 8; ++rr) { acc[rr][0] *= f8[rr]; acc[rr][1] *= f8[rr]; }
#pragma unroll 4
      for (int k = 0; k < WIN; ++k) {
        float4 pA = *(const float4*)&Pt[k * PT_P + r0];
        float4 pB = *(const float4*)&Pt[k * PT_P + r0 + 4];
        float2 yv = *(const float2*)&Yt[k * YT_P + e0];
        acc[0][0] = fmaf(pA.x, yv.x, acc[0][0]); acc[0][1] = fmaf(pA.x, yv.y, acc[0][1]);
        acc[1][0] = fmaf(pA.y, yv.x, acc[1][0]); acc[1][1] = fmaf(pA.y, yv.y, acc[1][1]);
        acc[2][0] = fmaf(pA.z, yv.x, acc[2][0]); acc[2][1] = fmaf(pA.z, yv.y, acc[2][1]);
        acc[3][0] = fmaf(pA.w, yv.x, acc[3][0]); acc[3][1] = fmaf(pA.w, yv.y, acc[3][1]);
        acc[4][0] = fmaf(pB.x, yv.x, acc[4][0]); acc[4][1] = fmaf(pB.x, yv.y, acc[4][1]);
        acc[5][0] = fmaf(pB.y, yv.x, acc[5][0]); acc[5][1] = fmaf(pB.y, yv.y, acc[5][1]);
        acc[6][0] = fmaf(pB.z, yv.x, acc[6][0]); acc[6][1] = fmaf(pB.z, yv.y, acc[6][1]);
        acc[7][0] = fmaf(pB.w, yv.x, acc[7][0]); acc[7][1] = fmaf(pB.w, yv.y, acc[7][1]);
      }
    }
  }

  // normalize + scatter (the unsort); per-row wave-contiguous 400B stores
  if (pvact) {
#pragma unroll
    for (int rr = 0; rr < 8; ++rr) {
      float is = 1.f / rsumS[r0 + rr];
      float* orow = attnO + (((size_t)(n * NS + u) * L) + lidxS[r0 + rr]) * CIN
                  + eh * EHC + e0;
      *(float2*)orow = make_float2(acc[rr][0] * is, acc[rr][1] * is);
    }
  }
}

// ---------------------------------------------------------------------------
// 1x1 Wout (K=800) + bias + residual -> out (N, 200, L). grid (256, N), block 256
// ---------------------------------------------------------------------------
__global__ __launch_bounds__(256) void k_wout(const float* __restrict__ attnO,
                                              const float* __restrict__ Wo,
                                              const float* __restrict__ bo,
                                              const float* __restrict__ in,
                                              float* __restrict__ out) {
  const int n  = blockIdx.y;
  const int l0 = blockIdx.x * 64;
  __shared__ __align__(16) char sm[44160];
  float* At = (float*)sm;            // [40][68]  10880 B
  float* Wt = (float*)(sm + 10880);  // [40][208] 33280 B
  const int pg = threadIdx.x >> 4, og = threadIdx.x & 15;
  const int tid = threadIdx.x;

  float acc[4][13];
#pragma unroll
  for (int p = 0; p < 4; ++p)
#pragma unroll
    for (int j = 0; j < 13; ++j) acc[p][j] = 0.f;

  for (int idx = tid; idx < 40 * 8; idx += 256)
    Wt[(idx >> 3) * 208 + 200 + (idx & 7)] = 0.f;

  for (int c0 = 0; c0 < 800; c0 += 40) {
    const int u = c0 / 200, e0 = c0 % 200;
    __syncthreads();
    for (int idx = tid; idx < 64 * 40; idx += 256) {
      int p = idx / 40, kk = idx % 40;
      At[kk * 68 + p] = attnO[(((size_t)(n * NS + u) * L) + l0 + p) * CIN + e0 + kk];
    }
    for (int idx = tid; idx < 200 * 40; idx += 256) {
      int oc = idx / 40, kk = idx % 40;
      Wt[kk * 208 + oc] = Wo[(size_t)oc * 800 + c0 + kk];
    }
    __syncthreads();
#pragma unroll 8
    for (int kk = 0; kk < 40; ++kk) {
      float4 av = *(const float4*)&At[kk * 68 + pg * 4];
      float a[4] = {av.x, av.y, av.z, av.w};
      float b[13];
#pragma unroll
      for (int j = 0; j < 13; ++j) b[j] = Wt[kk * 208 + og * 13 + j];
#pragma unroll
      for (int p = 0; p < 4; ++p)
#pragma unroll
        for (int j = 0; j < 13; ++j) acc[p][j] = fmaf(a[p], b[j], acc[p][j]);
    }
  }
  __syncthreads();

  // staged epilogue for coalesced stores
  float* Ot = (float*)sm;            // [104][64]
  for (int r = 0; r < 2; ++r) {
    const int ocb = r * 104;
    const int width = (r == 0) ? 104 : 96;
#pragma unroll
    for (int p = 0; p < 4; ++p)
#pragma unroll
      for (int j = 0; j < 13; ++j) {
        int oc = og * 13 + j;
        if (oc >= ocb && oc < ocb + width)
          Ot[(oc - ocb) * 64 + pg * 4 + p] = acc[p][j];
      }
    __syncthreads();
    for (int idx = tid; idx < width * 64; idx += 256) {
      int oc2 = idx >> 6, p = idx & 63;
      size_t o = ((size_t)n * CIN + ocb + oc2) * L + l0 + p;
      out[o] = Ot[oc2 * 64 + p] + bo[ocb + oc2] + in[o];
    }
    __syncthreads();
  }
}

// ---------------------------------------------------------------------------
extern "C" void kernel_launch(void* const* d_in, const int* in_sizes, int n_in,
                              void* d_out, int out_size, void* d_ws, size_t ws_size,
                              hipStream_t stream) {
  const float* in = (const float*)d_in[0];
  const int*   sl = (const int*)d_in[1];
  const float* Wx = (const float*)d_in[2];
  const float* Wy = (const float*)d_in[3];
  const float* Wo = (const float*)d_in[4];
  const float* bo = (const float*)d_in[5];
  float* out = (float*)d_out;

  // workspace layout (needs ~138.3 MB)
  float* xe   = (float*)d_ws;                           // 2*16384*50
  float* ye   = xe + (size_t)2 * L * CE;                // 2*16384*200
  float* attn = ye + (size_t)2 * L * CIN;               // 2*4*16384*200
  int*   perm = (int*)(attn + (size_t)2 * NS * L * CIN);
  int*   hist = perm + (size_t)2 * NS * L;
  int*   offs = hist + (size_t)2 * 128 * 128;

  k_conv3  <<<dim3(5, 64, 2),  256, 0, stream>>>(in, Wx, xe);
  k_wy     <<<dim3(256, 2),    256, 0, stream>>>(in, Wy, ye);
  k_hist   <<<256,             256, 0, stream>>>(sl, hist);
  k_scan   <<<2,               128, 0, stream>>>(hist, offs);
  k_scatter<<<256,             512, 0, stream>>>(sl, offs, perm);
  k_attn   <<<dim3(256, 4, 4), 512, 0, stream>>>(xe, ye, perm, attn);
  k_wout   <<<dim3(256, 2),    256, 0, stream>>>(attn, Wo, bo, in, out);
}

// Round 10
// 974.180 us; speedup vs baseline: 1.7800x; 1.1303x over previous
//
#include <hip/hip_runtime.h>
#include <hip/hip_bf16.h>
#include <math.h>

#define L      16384
#define CIN    200
#define CE     50
#define NS     4
#define KCL    256
#define WIN    64
#define NKEY   192

// ---------------------------------------------------------------------------
// conv3x3 reflect-pad -> partial x_embed, GEMM-style (k_wy template).
// grid (4 ic-groups, 64 row-pairs, 2 n), block 256.
// Block: 256 px (2 rows) x 52 oc (padded), K = 50 ic x 9 taps.
// Thread: 4 px x 13 oc. Weights read as wave-uniform LDS broadcasts.
// Partials summed by k_cred into xe.
// ---------------------------------------------------------------------------
#define KC    10
#define AT_S  132              // At row stride (130 used)
#define WT_S  64               // Wt oc stride (4 groups x 16)

__global__ __launch_bounds__(256) void k_conv3p(const float* __restrict__ in,
                                                const float* __restrict__ Wx,
                                                float* __restrict__ xp) {
  const int icg = blockIdx.x;          // 0..3
  const int rp  = blockIdx.y;          // 0..63
  const int n   = blockIdx.z;
  const int tid = threadIdx.x;
  const int ic0 = icg * 50;

  __shared__ __align__(16) float At[KC * 4 * AT_S];   // 21.1 KB
  __shared__ __align__(16) float Wt[KC * 9 * WT_S];   // 23.0 KB

  const int pxg = tid & 63;            // 64 groups of 4 px
  const int ocg = tid >> 6;            // wave-uniform! 4 groups of 13 oc
  const int px4 = pxg * 4;             // 0..252
  const int c0  = px4 & 127;           // col within row
  const int hr  = px4 >> 7;            // 0/1: which of the 2 output rows
  const int oc0 = ocg * 13;
  const int h0  = rp * 2;

  float acc[4][13];
#pragma unroll
  for (int p = 0; p < 4; ++p)
#pragma unroll
    for (int j = 0; j < 13; ++j) acc[p][j] = 0.f;

  const float* inN = in + ((size_t)n * CIN + ic0) * L;

  for (int st = 0; st < 5; ++st) {
    __syncthreads();
    // stage input: KC ic x 4 rows (h0-1..h0+2 reflected) x 130 cols (-1..128 refl)
    for (int idx = tid; idx < KC * 4 * 130; idx += 256) {
      int k = idx / 520, rem = idx % 520;
      int r = rem / 130, ci = rem % 130;
      int gr = h0 - 1 + r; gr = gr < 0 ? -gr : (gr > 127 ? 254 - gr : gr);
      int gc = ci - 1;     gc = gc < 0 ? -gc : (gc > 127 ? 254 - gc : gc);
      At[(k * 4 + r) * AT_S + ci] = inN[(size_t)(st * KC + k) * L + gr * 128 + gc];
    }
    // stage weights transposed: Wt[k][q][ocg*16 + j]
    for (int idx = tid; idx < KC * 9 * 52; idx += 256) {
      int k = idx / 468, rem = idx % 468;
      int q = rem / 52, s = rem % 52;
      int og = s / 13, j = s % 13;
      Wt[(k * 9 + q) * WT_S + og * 16 + j] =
          Wx[(size_t)(og * 13 + j) * (CIN * 9) + (size_t)(ic0 + st * KC + k) * 9 + q];
    }
    __syncthreads();

    for (int k = 0; k < KC; ++k) {
      float v[3][6];
#pragma unroll
      for (int dr = 0; dr < 3; ++dr) {
        const float* ar = &At[(k * 4 + hr + dr) * AT_S + c0];
        float4 a4 = *(const float4*)ar;
        float2 a2 = *(const float2*)(ar + 4);
        v[dr][0] = a4.x; v[dr][1] = a4.y; v[dr][2] = a4.z;
        v[dr][3] = a4.w; v[dr][4] = a2.x; v[dr][5] = a2.y;
      }
      const float* wk = &Wt[k * 9 * WT_S + ocg * 16];
#pragma unroll
      for (int q = 0; q < 9; ++q) {
        const int dr = q / 3, dc = q % 3;
        float4 w0 = *(const float4*)&wk[q * WT_S + 0];   // uniform broadcast
        float4 w1 = *(const float4*)&wk[q * WT_S + 4];
        float4 w2 = *(const float4*)&wk[q * WT_S + 8];
        float  wc = wk[q * WT_S + 12];
        float w[13] = {w0.x, w0.y, w0.z, w0.w, w1.x, w1.y, w1.z, w1.w,
                       w2.x, w2.y, w2.z, w2.w, wc};
#pragma unroll
        for (int j = 0; j < 13; ++j)
#pragma unroll
          for (int p = 0; p < 4; ++p)
            acc[p][j] = fmaf(v[dr][p + dc], w[j], acc[p][j]);
      }
    }
  }

  // write partials: xp[icg][n][l][oc], l = rp*256 + px4 + p
  float* xpN = xp + (size_t)(icg * 2 + n) * L * CE;
#pragma unroll
  for (int p = 0; p < 4; ++p) {
    float* row = xpN + (size_t)(rp * 256 + px4 + p) * CE + oc0;
#pragma unroll
    for (int j = 0; j < 13; ++j)
      if (oc0 + j < CE) row[j] = acc[p][j];
  }
}

// sum 4 ic-group partials -> xe (float4 grid-stride)
__global__ __launch_bounds__(256) void k_cred(const float* __restrict__ xp,
                                              float* __restrict__ xe) {
  const int tot4 = 2 * L * CE / 4;     // 409600
  int i = blockIdx.x * 256 + threadIdx.x;
  if (i < tot4) {
    const float4* p = (const float4*)xp;
    float4 a = p[i], b = p[tot4 + i], c = p[2 * tot4 + i], d = p[3 * tot4 + i];
    ((float4*)xe)[i] = make_float4(a.x + b.x + c.x + d.x, a.y + b.y + c.y + d.y,
                                   a.z + b.z + c.z + d.z, a.w + b.w + c.w + d.w);
  }
}

// ---------------------------------------------------------------------------
// 1x1 Wy -> y_embed (N, L, 200).  grid (256 l-tiles, N), block 256
// ---------------------------------------------------------------------------
__global__ __launch_bounds__(256) void k_wy(const float* __restrict__ in,
                                            const float* __restrict__ Wy,
                                            float* __restrict__ ye) {
  const int n  = blockIdx.y;
  const int l0 = blockIdx.x * 64;
  __shared__ __align__(16) float At[20][64];
  __shared__ __align__(16) float Wt[20][208];
  const int pg = threadIdx.x >> 4, og = threadIdx.x & 15;

  float acc[4][13];
#pragma unroll
  for (int p = 0; p < 4; ++p)
#pragma unroll
    for (int j = 0; j < 13; ++j) acc[p][j] = 0.f;

  for (int idx = threadIdx.x; idx < 20 * 8; idx += 256)
    Wt[idx >> 3][200 + (idx & 7)] = 0.f;

  const float* inN = in + (size_t)n * CIN * L + l0;
  for (int c0 = 0; c0 < CIN; c0 += 20) {
    __syncthreads();
    for (int idx = threadIdx.x; idx < 20 * 64; idx += 256) {
      int k = idx >> 6, p = idx & 63;
      At[k][p] = inN[(size_t)(c0 + k) * L + p];
    }
    for (int idx = threadIdx.x; idx < 200 * 20; idx += 256) {
      int oc = idx / 20, k = idx % 20;
      Wt[k][oc] = Wy[(size_t)oc * CIN + c0 + k];
    }
    __syncthreads();
#pragma unroll
    for (int k = 0; k < 20; ++k) {
      float4 av = *(const float4*)&At[k][pg * 4];
      float a[4] = {av.x, av.y, av.z, av.w};
      float b[13];
#pragma unroll
      for (int j = 0; j < 13; ++j) b[j] = Wt[k][og * 13 + j];
#pragma unroll
      for (int p = 0; p < 4; ++p)
#pragma unroll
        for (int j = 0; j < 13; ++j) acc[p][j] = fmaf(a[p], b[j], acc[p][j]);
    }
  }
#pragma unroll
  for (int p = 0; p < 4; ++p) {
    int l = l0 + pg * 4 + p;
    float* yrow = ye + ((size_t)n * L + l) * CIN;
#pragma unroll
    for (int j = 0; j < 13; ++j) {
      int oc = og * 13 + j;
      if (oc < CIN) yrow[oc] = acc[p][j];
    }
  }
}

// ---------------------------------------------------------------------------
// Stable counting sort of keys (u*100+label) -> 128 buckets (b = u*32+label).
// ---------------------------------------------------------------------------
__global__ __launch_bounds__(256) void k_hist(const int* __restrict__ sl,
                                              int* __restrict__ hist) {
  const int blk = blockIdx.x;           // n*128 + chunk
  const int n = blk >> 7, ch = blk & 127;
  __shared__ int h[128];
  if (threadIdx.x < 128) h[threadIdx.x] = 0;
  __syncthreads();
#pragma unroll
  for (int it = 0; it < 2; ++it) {
    int pos = ch * 512 + it * 256 + threadIdx.x;      // [0, 65536)
    int u = pos >> 14, l = pos & (L - 1);
    int lab = sl[((size_t)n * NS + u) * L + l] & 31;
    atomicAdd(&h[u * 32 + lab], 1);
  }
  __syncthreads();
  if (threadIdx.x < 128) hist[(blk << 7) + threadIdx.x] = h[threadIdx.x];
}

__global__ __launch_bounds__(128) void k_scan(const int* __restrict__ hist,
                                              int* __restrict__ offs) {
  const int n = blockIdx.x, b = threadIdx.x;
  __shared__ int tot[128];
  __shared__ int basebuf[128];
  int t = 0;
  for (int c = 0; c < 128; ++c) t += hist[(((size_t)n * 128 + c) << 7) + b];
  tot[b] = t;
  __syncthreads();
  if (b == 0) {
    int run = 0;
    for (int i = 0; i < 128; ++i) { basebuf[i] = run; run += tot[i]; }
  }
  __syncthreads();
  int run = basebuf[b];
  for (int c = 0; c < 128; ++c) {
    offs[(((size_t)n * 128 + c) << 7) + b] = run;
    run += hist[(((size_t)n * 128 + c) << 7) + b];
  }
}

__global__ __launch_bounds__(512) void k_scatter(const int* __restrict__ sl,
                                                 const int* __restrict__ offs,
                                                 int* __restrict__ perm) {
  const int blk = blockIdx.x;
  const int n = blk >> 7, ch = blk & 127;
  const int tid = threadIdx.x, wv = tid >> 6, lane = tid & 63;
  __shared__ int wh[8][128];
  for (int idx = tid; idx < 1024; idx += 512) ((int*)wh)[idx] = 0;
  __syncthreads();
  const int pos = ch * 512 + tid;
  const int u = pos >> 14, l = pos & (L - 1);
  const int b = u * 32 + (sl[((size_t)n * NS + u) * L + l] & 31);
  atomicAdd(&wh[wv][b], 1);
  int lr = 0;
  for (int s = 0; s < 64; ++s) {
    int ob = __shfl(b, s);
    lr += (s < lane && ob == b) ? 1 : 0;
  }
  __syncthreads();
  if (tid < 128) {
    int run = 0;
#pragma unroll
    for (int w = 0; w < 8; ++w) { int v = wh[w][tid]; wh[w][tid] = run; run += v; }
  }
  __syncthreads();
  const int rank = offs[(blk << 7) + b] + wh[wv][b] + lr;
  perm[(size_t)n * (NS * L) + rank] = pos;
}

// ---------------------------------------------------------------------------
// Windowed attention, flash-style, e-split across 2 blocks per window.
// grid (256 k, 4 u, 4 (n*2+eh)), block 512.  LDS ~72.5 KB -> 2 blocks/CU.
// ---------------------------------------------------------------------------
#define PT_P  68
#define QS_P  68
#define KS_P  68
#define YT_P  100
#define EHC   100

__global__ __launch_bounds__(512) void k_attn(const float* __restrict__ xe,
                                              const float* __restrict__ ye,
                                              const int* __restrict__ perm,
                                              float* __restrict__ attnO) {
  const int kcl = blockIdx.x;
  const int u   = blockIdx.y;
  const int n   = blockIdx.z >> 1;
  const int eh  = blockIdx.z & 1;
  const int tid = threadIdx.x;

  __shared__ __align__(16) float Qst[CE * QS_P];     // 13600 B
  __shared__ __align__(16) float Kst[CE * KS_P];     // 13600 B
  __shared__ __align__(16) float Pt[WIN * PT_P];     // 17408 B
  __shared__ __align__(16) float Yt[WIN * YT_P];     // 25600 B
  __shared__ int   lidxS[NKEY];
  __shared__ float rmaxS[WIN];
  __shared__ float rsumS[WIN];
  __shared__ float facS[WIN];

  if (tid < NKEY) {
    int kj = tid < 64 ? kcl
           : (tid < 128 ? ((kcl + KCL - 1) & (KCL - 1)) : ((kcl + 1) & (KCL - 1)));
    int p = (u << 14) + (kj << 6) + (tid & 63);
    lidxS[tid] = perm[(size_t)n * (NS * L) + p] & (L - 1);
  }
  if (tid < WIN) { rmaxS[tid] = -1e30f; rsumS[tid] = 0.f; }
  __syncthreads();

  // Q gather (raw): 8 lanes per row, transposed store Qst[c][j]
  {
    const int j = tid >> 3, c8 = tid & 7;
    const float* xrow = xe + ((size_t)n * L + lidxS[j]) * CE;
#pragma unroll
    for (int k = 0; k < 7; ++k) {
      int c = c8 + 8 * k;
      if (c < CE) Qst[c * QS_P + j] = xrow[c];
    }
  }

  // thread mappings
  const int ig = tid >> 5, jg = tid & 31;        // S: rows i0..i0+3, cols j0,j0+1
  const int i0 = ig * 4, j0 = jg * 2;
  const int rt = tid >> 6, lane = tid & 63;      // PV: rows r0..r0+7, cols e0,e0+1
  const int r0 = rt * 8, e0 = lane * 2;
  const bool pvact = lane < 50;

  float acc[8][2];
#pragma unroll
  for (int rr = 0; rr < 8; ++rr) { acc[rr][0] = 0.f; acc[rr][1] = 0.f; }

  const float* yeN = ye + (size_t)n * L * CIN + eh * EHC;

  for (int T = 0; T < 3; ++T) {
    const int jb = T * 64;
    if (T) __syncthreads();             // protect Kst/Yt/Pt from prev PV readers

    // K gather + fused L2-normalize (8 lanes per row, shfl_xor reduce)
    {
      const int j = tid >> 3, c8 = tid & 7;
      const float* xrow = xe + ((size_t)n * L + lidxS[jb + j]) * CE;
      float v[7];
      float ss = 0.f;
#pragma unroll
      for (int k = 0; k < 7; ++k) {
        int c = c8 + 8 * k;
        v[k] = (c < CE) ? xrow[c] : 0.f;
        ss = fmaf(v[k], v[k], ss);
      }
      ss += __shfl_xor(ss, 1); ss += __shfl_xor(ss, 2); ss += __shfl_xor(ss, 4);
      float inv = 1.f / fmaxf(sqrtf(ss), 5e-5f);
#pragma unroll
      for (int k = 0; k < 7; ++k) {
        int c = c8 + 8 * k;
        if (c < CE) Kst[c * KS_P + j] = v[k] * inv;
      }
    }
    // Y tile stage (this block's 100-col half), float4
    for (int idx = tid; idx < WIN * 25; idx += 512) {
      int j = idx / 25, c = idx % 25;
      *(float4*)&Yt[j * YT_P + c * 4] =
          *(const float4*)&yeN[(size_t)lidxS[jb + j] * CIN + c * 4];
    }
    __syncthreads();

    // S (64x64) + fused online softmax epilogue; Pt gets exp'd values
    {
      float s[4][2];
#pragma unroll
      for (int a = 0; a < 4; ++a) { s[a][0] = 0.f; s[a][1] = 0.f; }
      for (int c = 0; c < CE; ++c) {
        float4 qv = *(const float4*)&Qst[c * QS_P + i0];   // uniform broadcast
        float2 kv = *(const float2*)&Kst[c * KS_P + j0];   // per-lane
        s[0][0] = fmaf(qv.x, kv.x, s[0][0]); s[0][1] = fmaf(qv.x, kv.y, s[0][1]);
        s[1][0] = fmaf(qv.y, kv.x, s[1][0]); s[1][1] = fmaf(qv.y, kv.y, s[1][1]);
        s[2][0] = fmaf(qv.z, kv.x, s[2][0]); s[2][1] = fmaf(qv.z, kv.y, s[2][1]);
        s[3][0] = fmaf(qv.w, kv.x, s[3][0]); s[3][1] = fmaf(qv.w, kv.y, s[3][1]);
      }
      float nm[4], fc[4], ts[4];
#pragma unroll
      for (int a = 0; a < 4; ++a) {
        float tm = fmaxf(s[a][0], s[a][1]);
        tm = fmaxf(tm, __shfl_xor(tm, 1));
        tm = fmaxf(tm, __shfl_xor(tm, 2));
        tm = fmaxf(tm, __shfl_xor(tm, 4));
        tm = fmaxf(tm, __shfl_xor(tm, 8));
        tm = fmaxf(tm, __shfl_xor(tm, 16));
        float mo = rmaxS[i0 + a];
        nm[a] = fmaxf(mo, tm);
        fc[a] = __expf(mo - nm[a]);
        s[a][0] = __expf(s[a][0] - nm[a]);
        s[a][1] = __expf(s[a][1] - nm[a]);
        float t = s[a][0] + s[a][1];
        t += __shfl_xor(t, 1); t += __shfl_xor(t, 2); t += __shfl_xor(t, 4);
        t += __shfl_xor(t, 8); t += __shfl_xor(t, 16);
        ts[a] = t;
      }
      *(float4*)&Pt[(j0 + 0) * PT_P + i0] =
          make_float4(s[0][0], s[1][0], s[2][0], s[3][0]);
      *(float4*)&Pt[(j0 + 1) * PT_P + i0] =
          make_float4(s[0][1], s[1][1], s[2][1], s[3][1]);
      if (jg == 0) {
#pragma unroll
        for (int a = 0; a < 4; ++a) {
          rmaxS[i0 + a] = nm[a];
          rsumS[i0 + a] = rsumS[i0 + a] * fc[a] + ts[a];
          facS[i0 + a]  = fc[a];
        }
      }
    }
    __syncthreads();

    // PV: 8 rows x 2 cols per thread; P uniform b128, Y per-lane b64
    if (pvact) {
      float f8[8];
#pragma unroll
      for (int rr = 0; rr < 8; ++rr) f8[rr] = facS[r0 + rr];
#pragma unroll
      for (int rr = 0; rr < 8; ++rr) { acc[rr][0] *= f8[rr]; acc[rr][1] *= f8[rr]; }
#pragma unroll 4
      for (int k = 0; k < WIN; ++k) {
        float4 pA = *(const float4*)&Pt[k * PT_P + r0];
        float4 pB = *(const float4*)&Pt[k * PT_P + r0 + 4];
        float2 yv = *(const float2*)&Yt[k * YT_P + e0];
        acc[0][0] = fmaf(pA.x, yv.x, acc[0][0]); acc[0][1] = fmaf(pA.x, yv.y, acc[0][1]);
        acc[1][0] = fmaf(pA.y, yv.x, acc[1][0]); acc[1][1] = fmaf(pA.y, yv.y, acc[1][1]);
        acc[2][0] = fmaf(pA.z, yv.x, acc[2][0]); acc[2][1] = fmaf(pA.z, yv.y, acc[2][1]);
        acc[3][0] = fmaf(pA.w, yv.x, acc[3][0]); acc[3][1] = fmaf(pA.w, yv.y, acc[3][1]);
        acc[4][0] = fmaf(pB.x, yv.x, acc[4][0]); acc[4][1] = fmaf(pB.x, yv.y, acc[4][1]);
        acc[5][0] = fmaf(pB.y, yv.x, acc[5][0]); acc[5][1] = fmaf(pB.y, yv.y, acc[5][1]);
        acc[6][0] = fmaf(pB.z, yv.x, acc[6][0]); acc[6][1] = fmaf(pB.z, yv.y, acc[6][1]);
        acc[7][0] = fmaf(pB.w, yv.x, acc[7][0]); acc[7][1] = fmaf(pB.w, yv.y, acc[7][1]);
      }
    }
  }

  // normalize + scatter (the unsort); per-row wave-contiguous 400B stores
  if (pvact) {
#pragma unroll
    for (int rr = 0; rr < 8; ++rr) {
      float is = 1.f / rsumS[r0 + rr];
      float* orow = attnO + (((size_t)(n * NS + u) * L) + lidxS[r0 + rr]) * CIN
                  + eh * EHC + e0;
      *(float2*)orow = make_float2(acc[rr][0] * is, acc[rr][1] * is);
    }
  }
}

// ---------------------------------------------------------------------------
// 1x1 Wout (K=800) + bias + residual -> out (N, 200, L). grid (256, N), block 256
// ---------------------------------------------------------------------------
__global__ __launch_bounds__(256) void k_wout(const float* __restrict__ attnO,
                                              const float* __restrict__ Wo,
                                              const float* __restrict__ bo,
                                              const float* __restrict__ in,
                                              float* __restrict__ out) {
  const int n  = blockIdx.y;
  const int l0 = blockIdx.x * 64;
  __shared__ __align__(16) char sm[44160];
  float* At = (float*)sm;            // [40][68]  10880 B
  float* Wt = (float*)(sm + 10880);  // [40][208] 33280 B
  const int pg = threadIdx.x >> 4, og = threadIdx.x & 15;
  const int tid = threadIdx.x;

  float acc[4][13];
#pragma unroll
  for (int p = 0; p < 4; ++p)
#pragma unroll
    for (int j = 0; j < 13; ++j) acc[p][j] = 0.f;

  for (int idx = tid; idx < 40 * 8; idx += 256)
    Wt[(idx >> 3) * 208 + 200 + (idx & 7)] = 0.f;

  for (int c0 = 0; c0 < 800; c0 += 40) {
    const int u = c0 / 200, e0 = c0 % 200;
    __syncthreads();
    for (int idx = tid; idx < 64 * 40; idx += 256) {
      int p = idx / 40, kk = idx % 40;
      At[kk * 68 + p] = attnO[(((size_t)(n * NS + u) * L) + l0 + p) * CIN + e0 + kk];
    }
    for (int idx = tid; idx < 200 * 40; idx += 256) {
      int oc = idx / 40, kk = idx % 40;
      Wt[kk * 208 + oc] = Wo[(size_t)oc * 800 + c0 + kk];
    }
    __syncthreads();
#pragma unroll 8
    for (int kk = 0; kk < 40; ++kk) {
      float4 av = *(const float4*)&At[kk * 68 + pg * 4];
      float a[4] = {av.x, av.y, av.z, av.w};
      float b[13];
#pragma unroll
      for (int j = 0; j < 13; ++j) b[j] = Wt[kk * 208 + og * 13 + j];
#pragma unroll
      for (int p = 0; p < 4; ++p)
#pragma unroll
        for (int j = 0; j < 13; ++j) acc[p][j] = fmaf(a[p], b[j], acc[p][j]);
    }
  }
  __syncthreads();

  // staged epilogue for coalesced stores
  float* Ot = (float*)sm;            // [104][64]
  for (int r = 0; r < 2; ++r) {
    const int ocb = r * 104;
    const int width = (r == 0) ? 104 : 96;
#pragma unroll
    for (int p = 0; p < 4; ++p)
#pragma unroll
      for (int j = 0; j < 13; ++j) {
        int oc = og * 13 + j;
        if (oc >= ocb && oc < ocb + width)
          Ot[(oc - ocb) * 64 + pg * 4 + p] = acc[p][j];
      }
    __syncthreads();
    for (int idx = tid; idx < width * 64; idx += 256) {
      int oc2 = idx >> 6, p = idx & 63;
      size_t o = ((size_t)n * CIN + ocb + oc2) * L + l0 + p;
      out[o] = Ot[oc2 * 64 + p] + bo[ocb + oc2] + in[o];
    }
    __syncthreads();
  }
}

// ---------------------------------------------------------------------------
extern "C" void kernel_launch(void* const* d_in, const int* in_sizes, int n_in,
                              void* d_out, int out_size, void* d_ws, size_t ws_size,
                              hipStream_t stream) {
  const float* in = (const float*)d_in[0];
  const int*   sl = (const int*)d_in[1];
  const float* Wx = (const float*)d_in[2];
  const float* Wy = (const float*)d_in[3];
  const float* Wo = (const float*)d_in[4];
  const float* bo = (const float*)d_in[5];
  float* out = (float*)d_out;

  // workspace layout (~138.3 MB)
  float* xe   = (float*)d_ws;                           // 2*16384*50
  float* ye   = xe + (size_t)2 * L * CE;                // 2*16384*200
  float* attn = ye + (size_t)2 * L * CIN;               // 2*4*16384*200
  int*   perm = (int*)(attn + (size_t)2 * NS * L * CIN);
  int*   hist = perm + (size_t)2 * NS * L;
  int*   offs = hist + (size_t)2 * 128 * 128;
  // conv partials alias the attn region (dead until k_attn rewrites it)
  float* xpart = attn;                                  // 4*2*16384*50 floats

  k_conv3p <<<dim3(4, 64, 2),  256, 0, stream>>>(in, Wx, xpart);
  k_cred   <<<1600,            256, 0, stream>>>(xpart, xe);
  k_wy     <<<dim3(256, 2),    256, 0, stream>>>(in, Wy, ye);
  k_hist   <<<256,             256, 0, stream>>>(sl, hist);
  k_scan   <<<2,               128, 0, stream>>>(hist, offs);
  k_scatter<<<256,             512, 0, stream>>>(sl, offs, perm);
  k_attn   <<<dim3(256, 4, 4), 512, 0, stream>>>(xe, ye, perm, attn);
  k_wout   <<<dim3(256, 2),    256, 0, stream>>>(attn, Wo, bo, in, out);
}